// Round 8
// baseline (4322.124 us; speedup 1.0000x reference)
//
#include <hip/hip_runtime.h>

#define DEV __device__ __forceinline__

typedef _Float16 f16;
typedef _Float16 f16x8 __attribute__((ext_vector_type(8)));
typedef _Float16 f16x2 __attribute__((ext_vector_type(2)));
typedef float f32x4 __attribute__((ext_vector_type(4)));

DEV float sigmoidf_(float x) { return 1.0f / (1.0f + __expf(-x)); }
DEV float tanhf2_(float x)   { return 1.0f - 2.0f / (__expf(2.0f * x) + 1.0f); }

// async global->LDS, 16B per lane. LDS dest = wave-uniform base + lane*16.
DEV void load_lds16(const void* g, void* l) {
    __builtin_amdgcn_global_load_lds(
        (const __attribute__((address_space(1))) char*)(const char*)g,
        (__attribute__((address_space(3))) char*)(unsigned int)(unsigned long long)(char*)l,
        16, 0, 0);
}

// LDS 16x32(f16) tile swizzle: chunk (row,ck) lives at physical slot
// ck ^ (row&3) ^ ((row>>2)&3). Loader permutes the GLOBAL chunk per lane;
// reader picks the matching physical slot (XOR involution).
DEV int swz(int row, int ck) { return ck ^ (row & 3) ^ ((row >> 2) & 3); }

// ---------------------------------------------------------------------------
// LSTM weight prep (N512-block mapping). Col n (0..1023):
//   y=n>>9, wv=(n>>6)&7, j=(n>>4)&3, c=n&15 -> unit u=y*128+wv*16+c, gate g=j
//   torch src row = g*256+u  (torch gate order i,f,g,o)
// W0n [1024][288]: k<16 = w_ih (x), 16..31 = 0 (xpad zeros), 32.. = w_hh
// W1n [1024][512]: k<256 = w_ih (h0), else w_hh (h1)
// ---------------------------------------------------------------------------
__global__ void prep_w0n_kernel(const float* __restrict__ wih,
                                const float* __restrict__ whh,
                                f16* __restrict__ dst) {
    int idx = blockIdx.x * 256 + threadIdx.x;
    if (idx >= 1024 * 288) return;
    int rd = idx / 288, k = idx - rd * 288;
    int y = rd >> 9, wv = (rd >> 6) & 7, j = (rd >> 4) & 3, c = rd & 15;
    int u = y * 128 + wv * 16 + c;
    int src = j * 256 + u;
    float v;
    if (k < 16)       v = wih[src * 16 + k];
    else if (k < 32)  v = 0.f;
    else              v = whh[src * 256 + (k - 32)];
    dst[idx] = (f16)v;
}

__global__ void prep_w1n_kernel(const float* __restrict__ wih,
                                const float* __restrict__ whh,
                                f16* __restrict__ dst) {
    int idx = blockIdx.x * 256 + threadIdx.x;
    if (idx >= 1024 * 512) return;
    int rd = idx >> 9, k = idx & 511;
    int y = rd >> 9, wv = (rd >> 6) & 7, j = (rd >> 4) & 3, c = rd & 15;
    int u = y * 128 + wv * 16 + c;
    int src = j * 256 + u;
    float v = (k < 256) ? wih[src * 256 + k] : whh[src * 256 + (k - 256)];
    dst[idx] = (f16)v;
}

__global__ void prep_bias4_kernel(const float* __restrict__ bi,
                                  const float* __restrict__ bh,
                                  float* __restrict__ dst) {  // [1024] = [u*4+g]
    int idx = blockIdx.x * 256 + threadIdx.x;
    if (idx >= 1024) return;
    int u = idx >> 2, g = idx & 3;
    dst[idx] = bi[g * 256 + u] + bh[g * 256 + u];
}

// xpad [60][Mpad64][32] f16: cols 0..15 = x_seq[m][t][:], rest zero
__global__ void prep_xpad_kernel(const float* __restrict__ x, f16* __restrict__ xpad,
                                 int Nn, int Mpad64) {
    int idx = blockIdx.x * 256 + threadIdx.x;
    if (idx >= 60 * Nn * 16) return;
    int f = idx & 15;
    int tm = idx >> 4;
    int t = tm / Nn, m = tm - t * Nn;
    xpad[((size_t)t * Mpad64 + m) * 32 + f] = (f16)x[(size_t)m * 960 + t * 16 + f];
}

// generic [K,N] fp32 -> [N,K] fp16 transpose (GAT / fc1 weights)
__global__ void prep_wt_kernel(const float* __restrict__ src, f16* __restrict__ dst,
                               int K, int N) {
    int idx = blockIdx.x * 256 + threadIdx.x;
    if (idx >= K * N) return;
    int n = idx / K, k = idx - n * K;
    dst[idx] = (f16)src[(size_t)k * N + n];
}

// ---------------------------------------------------------------------------
// LSTM step, M64 x N512 tile. 512 threads = 8 waves; wave w owns n-slice
// [w*64, +64) over all 64 rows. Uniform control flow: every wave loads its
// 4 B tiles + A tile (w&3) (waves w and w+4 duplicate identical bytes).
// ---------------------------------------------------------------------------
DEV void lstm64_loads(const f16* __restrict__ Wtn0, int K, int kcAll,
                      const f16* __restrict__ asrc, int lda,
                      f16* __restrict__ sA, f16* __restrict__ sB,
                      int w, int arow, int achk)
{
    const f16* bp = Wtn0 + (size_t)(w * 64 + arow) * K + (size_t)kcAll * 32 + achk;
#pragma unroll
    for (int j = 0; j < 4; ++j)
        load_lds16(bp + (size_t)(j * 16) * K, sB + (w * 4 + j) * 512);
    const f16* ap = asrc + (size_t)((w & 3) * 16 + arow) * lda + achk;
    load_lds16(ap, sA + (w & 3) * 512);
}

DEV void lstm64_mfma(const f16* __restrict__ sA, const f16* __restrict__ sB,
                     f32x4 (&acc)[4][4], int frow, int fsl, int w)
{
    f16x8 af[4], bf[4];
#pragma unroll
    for (int i = 0; i < 4; ++i)
        af[i] = *(const f16x8*)&sA[i * 512 + frow * 32 + fsl];
#pragma unroll
    for (int j = 0; j < 4; ++j)
        bf[j] = *(const f16x8*)&sB[(w * 4 + j) * 512 + frow * 32 + fsl];
#pragma unroll
    for (int i = 0; i < 4; ++i)
#pragma unroll
        for (int j = 0; j < 4; ++j)
            acc[i][j] = __builtin_amdgcn_mfma_f32_16x16x32_f16(af[i], bf[j], acc[i][j], 0, 0, 0);
}

DEV void lstm64_core(
    f16* __restrict__ sA, f16* __restrict__ sB,
    const f16* __restrict__ src0, int lda0, int kc0,
    const f16* __restrict__ src1, int lda1, int kc1,
    const f16* __restrict__ Wt, int K,
    const float* __restrict__ bias4,
    float* __restrict__ c_state,
    f16* __restrict__ hOut, int ldh, int offh,
    int M)
{
    const int tid = threadIdx.x;
    const int w = tid >> 6, lane = tid & 63;
    const int arow = lane >> 2;
    const int achk = swz(arow, lane & 3) * 8;
    const int frow = lane & 15, l4 = lane >> 4;
    const int fsl = swz(frow, l4) * 8;
    const int m0 = blockIdx.x * 64;
    const f16* Wtn0 = Wt + (size_t)(blockIdx.y * 512) * K;

    f32x4 acc[4][4] = {};
    int kcAll = 0;
    for (int kc = 0; kc < kc0; ++kc, ++kcAll) {
        __syncthreads();
        lstm64_loads(Wtn0, K, kcAll, src0 + (size_t)m0 * lda0 + kc * 32, lda0,
                     sA, sB, w, arow, achk);
        __syncthreads();
        lstm64_mfma(sA, sB, acc, frow, fsl, w);
    }
    for (int kc = 0; kc < kc1; ++kc, ++kcAll) {
        __syncthreads();
        lstm64_loads(Wtn0, K, kcAll, src1 + (size_t)m0 * lda1 + kc * 32, lda1,
                     sA, sB, w, arow, achk);
        __syncthreads();
        lstm64_mfma(sA, sB, acc, frow, fsl, w);
    }

    // epilogue: lane owns unit u; acc[i][j][r] = gate j of row m
    const int u = blockIdx.y * 128 + w * 16 + frow;
    const float4 bb = *(const float4*)&bias4[u * 4];
#pragma unroll
    for (int i = 0; i < 4; ++i) {
#pragma unroll
        for (int r = 0; r < 4; ++r) {
            int m = m0 + i * 16 + l4 * 4 + r;
            if (m < M) {
                float gi = sigmoidf_(acc[i][0][r] + bb.x);
                float gf = sigmoidf_(acc[i][1][r] + bb.y);
                float gg = tanhf2_(acc[i][2][r] + bb.z);
                float go = sigmoidf_(acc[i][3][r] + bb.w);
                float cold = c_state[(size_t)m * 256 + u];
                float cn = gf * cold + gi * gg;
                c_state[(size_t)m * 256 + u] = cn;
                hOut[(size_t)m * ldh + offh + u] = (f16)(go * tanhf2_(cn));
            }
        }
    }
}

// solo one-layer step
__global__ __launch_bounds__(512) void lstm64_kernel(
    const f16* __restrict__ src0, int lda0, int kc0,
    const f16* __restrict__ src1, int lda1, int kc1,
    const f16* __restrict__ Wt, int K,
    const float* __restrict__ bias4, float* __restrict__ c_state,
    f16* __restrict__ hOut, int ldh, int offh, int M)
{
    __shared__ __align__(16) f16 sA[4 * 512];
    __shared__ __align__(16) f16 sB[32 * 512];
    lstm64_core(sA, sB, src0, lda0, kc0, src1, lda1, kc1,
                Wt, K, bias4, c_state, hOut, ldh, offh, M);
}

// merged: z=0 -> L1(k) [reads A1cur full, writes h1 -> A1next+256],
//         z=1 -> L0(k+1) [reads xpad(k+1) + A1cur cols 0..255, writes h0 -> A1next+0]
__global__ __launch_bounds__(512) void lstm64_dual_kernel(
    const f16* __restrict__ A1cur, f16* __restrict__ A1next,
    const f16* __restrict__ W1, const float* __restrict__ b1, float* __restrict__ c1,
    const f16* __restrict__ xslice,
    const f16* __restrict__ W0, const float* __restrict__ b0, float* __restrict__ c0,
    int M)
{
    __shared__ __align__(16) f16 sA[4 * 512];
    __shared__ __align__(16) f16 sB[32 * 512];
    if (blockIdx.z == 0)
        lstm64_core(sA, sB, A1cur, 512, 16, nullptr, 0, 0,
                    W1, 512, b1, c1, A1next, 512, 256, M);
    else
        lstm64_core(sA, sB, xslice, 32, 1, A1cur, 512, 8,
                    W0, 288, b0, c0, A1next, 512, 0, M);
}

// ---------------------------------------------------------------------------
// Generic f16 MFMA GEMM: C = act(A[M,lda(K cols)] @ Bt[N,K]^T + bias)
// ---------------------------------------------------------------------------
__global__ __launch_bounds__(256) void gemm16_kernel(
    const f16* __restrict__ A, int lda,
    const f16* __restrict__ Bt, int K,
    const float* __restrict__ bias,
    f16* __restrict__ C16, float* __restrict__ C32, int ldc,
    int act, int M)
{
    __shared__ __align__(16) f16 sA[128 * 32];
    __shared__ __align__(16) f16 sB[128 * 32];
    const int tid = threadIdx.x;
    const int w = tid >> 6, lane = tid & 63;
    const int m0 = blockIdx.x * 128, n0 = blockIdx.y * 128;
    const int arow = lane >> 2;
    const int achk = swz(arow, lane & 3) * 8;
    const int frow = lane & 15, l4 = lane >> 4;
    const int fsl = swz(frow, l4) * 8;
    const int wr = (w >> 1) * 64, wcn = (w & 1) * 64;

    f32x4 acc[4][4] = {};

    for (int k0 = 0; k0 < K; k0 += 32) {
        __syncthreads();
#pragma unroll
        for (int c = 0; c < 2; ++c) {
            int R = c * 64 + w * 16;
            load_lds16(A + (size_t)(m0 + R + arow) * lda + k0 + achk, sA + R * 32);
            load_lds16(Bt + (size_t)(n0 + R + arow) * K + k0 + achk, sB + R * 32);
        }
        __syncthreads();
        f16x8 af[4], bf[4];
#pragma unroll
        for (int i = 0; i < 4; ++i)
            af[i] = *(const f16x8*)&sA[(wr + i * 16 + frow) * 32 + fsl];
#pragma unroll
        for (int j = 0; j < 4; ++j)
            bf[j] = *(const f16x8*)&sB[(wcn + j * 16 + frow) * 32 + fsl];
#pragma unroll
        for (int i = 0; i < 4; ++i)
#pragma unroll
            for (int j = 0; j < 4; ++j)
                acc[i][j] = __builtin_amdgcn_mfma_f32_16x16x32_f16(af[i], bf[j], acc[i][j], 0, 0, 0);
    }

    const int rbase = m0 + wr + (lane >> 4) * 4;
#pragma unroll
    for (int i = 0; i < 4; ++i) {
#pragma unroll
        for (int r = 0; r < 4; ++r) {
            int m = rbase + i * 16 + r;
            if (m >= M) continue;
#pragma unroll
            for (int j = 0; j < 4; ++j) {
                int n = n0 + wcn + j * 16 + (lane & 15);
                float v = acc[i][j][r] + bias[n];
                if (act == 1) v = fmaxf(v, 0.f);
                if (C16) C16[(size_t)m * ldc + n] = (f16)v;
                else     C32[(size_t)m * ldc + n] = v;
            }
        }
    }
}

// dual-B variant: y<4 -> (Btl,biasl,Cl), y>=4 -> (Btr,biasr,Cr). fp16 out.
__global__ __launch_bounds__(256) void gemm16_dual_kernel(
    const f16* __restrict__ A, int lda,
    const f16* __restrict__ Btl, const f16* __restrict__ Btr, int K,
    const float* __restrict__ biasl, const float* __restrict__ biasr,
    f16* __restrict__ Cl, f16* __restrict__ Cr, int ldc, int M)
{
    __shared__ __align__(16) f16 sA[128 * 32];
    __shared__ __align__(16) f16 sB[128 * 32];
    const int side = blockIdx.y >> 2;
    const f16* Bt = side ? Btr : Btl;
    const float* bias = side ? biasr : biasl;
    f16* C16 = side ? Cr : Cl;
    const int tid = threadIdx.x;
    const int w = tid >> 6, lane = tid & 63;
    const int m0 = blockIdx.x * 128, n0 = (blockIdx.y & 3) * 128;
    const int arow = lane >> 2;
    const int achk = swz(arow, lane & 3) * 8;
    const int frow = lane & 15, l4 = lane >> 4;
    const int fsl = swz(frow, l4) * 8;
    const int wr = (w >> 1) * 64, wcn = (w & 1) * 64;

    f32x4 acc[4][4] = {};

    for (int k0 = 0; k0 < K; k0 += 32) {
        __syncthreads();
#pragma unroll
        for (int c = 0; c < 2; ++c) {
            int R = c * 64 + w * 16;
            load_lds16(A + (size_t)(m0 + R + arow) * lda + k0 + achk, sA + R * 32);
            load_lds16(Bt + (size_t)(n0 + R + arow) * K + k0 + achk, sB + R * 32);
        }
        __syncthreads();
        f16x8 af[4], bf[4];
#pragma unroll
        for (int i = 0; i < 4; ++i)
            af[i] = *(const f16x8*)&sA[(wr + i * 16 + frow) * 32 + fsl];
#pragma unroll
        for (int j = 0; j < 4; ++j)
            bf[j] = *(const f16x8*)&sB[(wcn + j * 16 + frow) * 32 + fsl];
#pragma unroll
        for (int i = 0; i < 4; ++i)
#pragma unroll
            for (int j = 0; j < 4; ++j)
                acc[i][j] = __builtin_amdgcn_mfma_f32_16x16x32_f16(af[i], bf[j], acc[i][j], 0, 0, 0);
    }

    const int rbase = m0 + wr + (lane >> 4) * 4;
#pragma unroll
    for (int i = 0; i < 4; ++i) {
#pragma unroll
        for (int r = 0; r < 4; ++r) {
            int m = rbase + i * 16 + r;
            if (m >= M) continue;
#pragma unroll
            for (int j = 0; j < 4; ++j) {
                int n = n0 + wcn + j * 16 + (lane & 15);
                float v = acc[i][j][r] + bias[n];
                C16[(size_t)m * ldc + n] = (f16)v;
            }
        }
    }
}

// ---------------------------------------------------------------------------
// Edge preprocessing
// ---------------------------------------------------------------------------
__global__ void mean_sum_kernel(const float* __restrict__ a, int n, float* __restrict__ out) {
    __shared__ float s[256];
    float loc = 0.f;
    for (int i = blockIdx.x * 256 + threadIdx.x; i < n; i += gridDim.x * 256) loc += a[i];
    s[threadIdx.x] = loc;
    __syncthreads();
    for (int off = 128; off; off >>= 1) {
        if (threadIdx.x < off) s[threadIdx.x] += s[threadIdx.x + off];
        __syncthreads();
    }
    if (threadIdx.x == 0) atomicAdd(out, s[0]);
}

__global__ void hist_kernel(const int* __restrict__ ei, int Ne, int Nn,
                            int* __restrict__ counts) {
    int e = blockIdx.x * 256 + threadIdx.x;
    if (e >= Ne + Nn) return;
    int d = (e < Ne) ? ei[Ne + e] : (e - Ne);
    atomicAdd(&counts[d], 1);
}

__global__ void scan_kernel(const int* __restrict__ counts, int* __restrict__ offsets, int n) {
    __shared__ int s[256];
    int tid = threadIdx.x;
    int chunk = (n + 255) / 256;
    int b = tid * chunk;
    int loc = 0;
    for (int j = 0; j < chunk; ++j) { int i = b + j; if (i < n) loc += counts[i]; }
    s[tid] = loc;
    __syncthreads();
    for (int off = 1; off < 256; off <<= 1) {
        int v = (tid >= off) ? s[tid - off] : 0;
        __syncthreads();
        s[tid] += v;
        __syncthreads();
    }
    int run = (tid == 0) ? 0 : s[tid - 1];
    for (int j = 0; j < chunk; ++j) {
        int i = b + j;
        if (i < n) { offsets[i] = run; run += counts[i]; }
    }
    if (tid == 255) offsets[n] = run;
}

__global__ void scatter_kernel(const int* __restrict__ ei, const float* __restrict__ ea,
                               const float* __restrict__ sump, float inv_ne, int Ne, int Nn,
                               int* __restrict__ cursor, int* __restrict__ src_sorted,
                               float* __restrict__ ea_sorted) {
    int e = blockIdx.x * 256 + threadIdx.x;
    if (e >= Ne + Nn) return;
    int s, d; float a;
    if (e < Ne) { s = ei[e]; d = ei[Ne + e]; a = ea[e]; }
    else        { s = e - Ne; d = s; a = sump[0] * inv_ne; }
    int pos = atomicAdd(&cursor[d], 1);
    src_sorted[pos] = s;
    ea_sorted[pos] = a;
}

// ---------------------------------------------------------------------------
// GATv2 attention + aggregation (fp16 xl/xr), one block per dst node.
// ---------------------------------------------------------------------------
__global__ __launch_bounds__(256) void gat_aggregate_kernel(
    const f16* __restrict__ xl, const f16* __restrict__ xr,
    const float* __restrict__ we, const float* __restrict__ att,
    const float* __restrict__ bias,
    const int* __restrict__ offsets, const int* __restrict__ src_sorted,
    const float* __restrict__ ea_sorted,
    float* __restrict__ logit_buf, f16* __restrict__ out, int ldo, int N)
{
    __shared__ float s_xr[512], s_we[512], s_att[512];
    __shared__ float s_wmax[32], s_mx[8], s_den[8], s_rden[8];
    __shared__ float s_alpha[256];
    __shared__ int s_src[32];
    const int i = blockIdx.x;
    const int tid = threadIdx.x;
    s_xr[tid]       = (float)xr[(size_t)i * 512 + tid];
    s_xr[tid + 256] = (float)xr[(size_t)i * 512 + tid + 256];
    s_we[tid] = we[tid]; s_we[tid + 256] = we[tid + 256];
    s_att[tid] = att[tid]; s_att[tid + 256] = att[tid + 256];
    if (tid < 8) s_den[tid] = 0.f;
    __syncthreads();

    const int beg = offsets[i], end = offsets[i + 1];
    const int w = tid >> 6, lane = tid & 63;

    float wm[4] = {-1e30f, -1e30f, -1e30f, -1e30f};
    for (int e = beg + w; e < end; e += 4) {
        int s = src_sorted[e];
        float a = ea_sorted[e];
        float part[4];
#pragma unroll
        for (int cc = 0; cc < 4; ++cc) {
            int col = cc * 128 + lane * 2;
            f16x2 xv = *(const f16x2*)&xl[(size_t)s * 512 + col];
            float v0 = (float)xv.x + s_xr[col]     + a * s_we[col];
            float v1 = (float)xv.y + s_xr[col + 1] + a * s_we[col + 1];
            v0 = (v0 > 0.f) ? v0 : 0.2f * v0;
            v1 = (v1 > 0.f) ? v1 : 0.2f * v1;
            part[cc] = v0 * s_att[col] + v1 * s_att[col + 1];
        }
#pragma unroll
        for (int off = 16; off; off >>= 1)
#pragma unroll
            for (int cc = 0; cc < 4; ++cc) part[cc] += __shfl_xor(part[cc], off);
        if ((lane & 31) == 0) {
            int hb = lane >> 5;
#pragma unroll
            for (int cc = 0; cc < 4; ++cc) {
                logit_buf[(size_t)e * 8 + 2 * cc + hb] = part[cc];
                wm[cc] = fmaxf(wm[cc], part[cc]);
            }
        }
    }
    if ((lane & 31) == 0) {
        int hb = lane >> 5;
#pragma unroll
        for (int cc = 0; cc < 4; ++cc) s_wmax[w * 8 + 2 * cc + hb] = wm[cc];
    }
    __syncthreads();
    if (tid < 8) {
        float m = fmaxf(fmaxf(s_wmax[tid], s_wmax[8 + tid]),
                        fmaxf(s_wmax[16 + tid], s_wmax[24 + tid]));
        s_mx[tid] = m;
    }
    __syncthreads();

    for (int e = beg + tid; e < end; e += 256) {
#pragma unroll
        for (int h = 0; h < 8; ++h) {
            float ex = __expf(logit_buf[(size_t)e * 8 + h] - s_mx[h]);
            logit_buf[(size_t)e * 8 + h] = ex;
            atomicAdd(&s_den[h], ex);
        }
    }
    __syncthreads();
    if (tid < 8) s_rden[tid] = 1.f / s_den[tid];
    __syncthreads();

    float acc0 = 0.f, acc1 = 0.f;
    const int c2 = tid * 2, hh = tid >> 5;
    for (int chunk = beg; chunk < end; chunk += 32) {
        int cnt = min(32, end - chunk);
        if (tid < cnt) s_src[tid] = src_sorted[chunk + tid];
        int eo = tid >> 3, hq = tid & 7;
        if (eo < cnt) s_alpha[tid] = logit_buf[(size_t)(chunk + eo) * 8 + hq] * s_rden[hq];
        __syncthreads();
        for (int j = 0; j < cnt; ++j) {
            int s = s_src[j];
            f16x2 xv = *(const f16x2*)&xl[(size_t)s * 512 + c2];
            float al = s_alpha[j * 8 + hh];
            acc0 += al * (float)xv.x;
            acc1 += al * (float)xv.y;
        }
        __syncthreads();
    }
    float v0 = acc0 + bias[c2];
    float v1 = acc1 + bias[c2 + 1];
    v0 = (v0 > 0.f) ? v0 : __expf(v0) - 1.f;
    v1 = (v1 > 0.f) ? v1 : __expf(v1) - 1.f;
    f16x2 ov; ov.x = (f16)v0; ov.y = (f16)v1;
    *(f16x2*)&out[(size_t)i * ldo + c2] = ov;
}

// fc2: out[n] = H[n,:512] . w + b (fp32)
__global__ void fc2_kernel(const float* __restrict__ H, const float* __restrict__ w,
                           const float* __restrict__ b, float* __restrict__ out, int N) {
    int wv = threadIdx.x >> 6, lane = threadIdx.x & 63;
    int node = blockIdx.x * 4 + wv;
    if (node >= N) return;
    float s = 0.f;
#pragma unroll
    for (int j = 0; j < 8; ++j)
        s += H[(size_t)node * 512 + j * 64 + lane] * w[j * 64 + lane];
#pragma unroll
    for (int off = 32; off; off >>= 1) s += __shfl_xor(s, off, 64);
    if (lane == 0) out[node] = s + b[0];
}

// ---------------------------------------------------------------------------
extern "C" void kernel_launch(void* const* d_in, const int* in_sizes, int n_in,
                              void* d_out, int out_size, void* d_ws, size_t ws_size,
                              hipStream_t stream) {
    const float* x_seq     = (const float*)d_in[0];
    const int*   edge_index= (const int*)d_in[1];
    const float* edge_attr = (const float*)d_in[2];
    const float* w_ih0 = (const float*)d_in[3];
    const float* w_hh0 = (const float*)d_in[4];
    const float* b_ih0 = (const float*)d_in[5];
    const float* b_hh0 = (const float*)d_in[6];
    const float* w_ih1 = (const float*)d_in[7];
    const float* w_hh1 = (const float*)d_in[8];
    const float* b_ih1 = (const float*)d_in[9];
    const float* b_hh1 = (const float*)d_in[10];
    const float* g0_wl = (const float*)d_in[11];
    const float* g0_bl = (const float*)d_in[12];
    const float* g0_wr = (const float*)d_in[13];
    const float* g0_br = (const float*)d_in[14];
    const float* g0_we = (const float*)d_in[15];
    const float* g0_att= (const float*)d_in[16];
    const float* g0_bias=(const float*)d_in[17];
    const float* g1_wl = (const float*)d_in[18];
    const float* g1_bl = (const float*)d_in[19];
    const float* g1_wr = (const float*)d_in[20];
    const float* g1_br = (const float*)d_in[21];
    const float* g1_we = (const float*)d_in[22];
    const float* g1_att= (const float*)d_in[23];
    const float* g1_bias=(const float*)d_in[24];
    const float* fc1_w = (const float*)d_in[25];
    const float* fc1_b = (const float*)d_in[26];
    const float* fc2_w = (const float*)d_in[27];
    const float* fc2_b = (const float*)d_in[28];
    float* out = (float*)d_out;

    const int Nn = in_sizes[0] / (60 * 16);   // 10000
    const int Ne = in_sizes[1] / 2;           // 320000
    const int Etot = Ne + Nn;
    const int MT = (Nn + 127) / 128;          // 79  (128-row tiles, GAT/fc GEMMs)
    const int Mpad = MT * 128;                // 10112
    const int MT64 = (Nn + 63) / 64;          // 157 (64-row tiles, LSTM)
    const int Mpad64 = MT64 * 64;             // 10048

    size_t off = 0;
    auto alloc = [&](size_t bytes) -> void* {
        void* r = (char*)d_ws + off;
        off += (bytes + 255) & ~(size_t)255;
        return r;
    };
    f16* W0n   = (f16*)alloc((size_t)1024 * 288 * 2);
    f16* W1n   = (f16*)alloc((size_t)1024 * 512 * 2);
    float* b40 = (float*)alloc(1024 * 4);
    float* b41 = (float*)alloc(1024 * 4);
    f16* xpad  = (f16*)alloc((size_t)60 * Mpad64 * 32 * 2);
    f16* A1b[2]; A1b[0] = (f16*)alloc((size_t)Mpad64 * 512 * 2);
                 A1b[1] = (f16*)alloc((size_t)Mpad64 * 512 * 2);
    float* c0s = (float*)alloc((size_t)Mpad64 * 256 * 4);
    float* c1s = (float*)alloc((size_t)Mpad64 * 256 * 4);
    f16* Wg0l  = (f16*)alloc((size_t)512 * 256 * 2);
    f16* Wg0r  = (f16*)alloc((size_t)512 * 256 * 2);
    f16* Wg1l  = (f16*)alloc((size_t)512 * 512 * 2);
    f16* Wg1r  = (f16*)alloc((size_t)512 * 512 * 2);
    f16* Wfc1  = (f16*)alloc((size_t)512 * 768 * 2);
    f16* fused = (f16*)alloc((size_t)Mpad * 768 * 2);
    f16* xlbuf = (f16*)alloc((size_t)Mpad * 512 * 2);
    f16* xrbuf = (f16*)alloc((size_t)Mpad * 512 * 2);
    f16* gbuf  = (f16*)alloc((size_t)Mpad * 512 * 2);
    float* hfc1= (float*)alloc((size_t)Mpad * 512 * 4);
    float* logit_buf = (float*)alloc((size_t)Etot * 8 * 4);
    int* counts  = (int*)alloc((size_t)Nn * 4);
    int* offsets = (int*)alloc((size_t)(Nn + 1) * 4);
    int* cursor  = (int*)alloc((size_t)Nn * 4);
    int* src_sorted = (int*)alloc((size_t)Etot * 4);
    float* ea_sorted = (float*)alloc((size_t)Etot * 4);
    float* meanp = (float*)alloc(256);

    // ---- weight / state prep ----
    prep_w0n_kernel<<<dim3((1024 * 288 + 255) / 256), 256, 0, stream>>>(w_ih0, w_hh0, W0n);
    prep_w1n_kernel<<<dim3((1024 * 512 + 255) / 256), 256, 0, stream>>>(w_ih1, w_hh1, W1n);
    prep_bias4_kernel<<<dim3(4), 256, 0, stream>>>(b_ih0, b_hh0, b40);
    prep_bias4_kernel<<<dim3(4), 256, 0, stream>>>(b_ih1, b_hh1, b41);
    prep_wt_kernel<<<dim3((256 * 512 + 255) / 256), 256, 0, stream>>>(g0_wl, Wg0l, 256, 512);
    prep_wt_kernel<<<dim3((256 * 512 + 255) / 256), 256, 0, stream>>>(g0_wr, Wg0r, 256, 512);
    prep_wt_kernel<<<dim3((512 * 512 + 255) / 256), 256, 0, stream>>>(g1_wl, Wg1l, 512, 512);
    prep_wt_kernel<<<dim3((512 * 512 + 255) / 256), 256, 0, stream>>>(g1_wr, Wg1r, 512, 512);
    prep_wt_kernel<<<dim3((768 * 512 + 255) / 256), 256, 0, stream>>>(fc1_w, Wfc1, 768, 512);
    hipMemsetAsync(xpad, 0, (size_t)60 * Mpad64 * 32 * 2, stream);
    hipMemsetAsync(A1b[0], 0, (size_t)Mpad64 * 512 * 2, stream);
    hipMemsetAsync(A1b[1], 0, (size_t)Mpad64 * 512 * 2, stream);
    hipMemsetAsync(c0s, 0, (size_t)Mpad64 * 256 * 4, stream);
    hipMemsetAsync(c1s, 0, (size_t)Mpad64 * 256 * 4, stream);
    prep_xpad_kernel<<<dim3((60 * Nn * 16 + 255) / 256), 256, 0, stream>>>(x_seq, xpad, Nn, Mpad64);

    // ---- edge prep (CSR by dst) ----
    hipMemsetAsync(meanp, 0, 4, stream);
    hipMemsetAsync(counts, 0, (size_t)Nn * 4, stream);
    mean_sum_kernel<<<dim3(256), 256, 0, stream>>>(edge_attr, Ne, meanp);
    hist_kernel<<<dim3((Etot + 255) / 256), 256, 0, stream>>>(edge_index, Ne, Nn, counts);
    scan_kernel<<<dim3(1), 256, 0, stream>>>(counts, offsets, Nn);
    hipMemcpyAsync(cursor, offsets, (size_t)Nn * 4, hipMemcpyDeviceToDevice, stream);
    scatter_kernel<<<dim3((Etot + 255) / 256), 256, 0, stream>>>(
        edge_index, edge_attr, meanp, 1.0f / (float)Ne, Ne, Nn, cursor, src_sorted, ea_sorted);

    // ---- 2-layer LSTM, 60 steps; L1(k) + L0(k+1) co-scheduled ----
    // A1b[p] holds [h0(t) | h1(t-1)] when L1(t) reads it (p = t&1).
    dim3 sgrid(MT64, 2);
    dim3 dgrid(MT64, 2, 2);
    // L0(0): x_0 + h0(-1)=0 (A1b[1], zeroed) -> h0(0) into A1b[0] cols 0..255
    lstm64_kernel<<<sgrid, 512, 0, stream>>>(
        xpad, 32, 1, A1b[1], 512, 8, W0n, 288, b40, c0s, A1b[0], 512, 0, Nn);
    // merged L1(k) + L0(k+1), k = 0..58
    for (int k = 0; k < 59; ++k) {
        lstm64_dual_kernel<<<dgrid, 512, 0, stream>>>(
            A1b[k & 1], A1b[(k + 1) & 1],
            W1n, b41, c1s,
            xpad + (size_t)(k + 1) * Mpad64 * 32,
            W0n, b40, c0s, Nn);
    }
    // L1(59): reads A1b[1] = [h0(59) | h1(58)], writes h1(59) -> fused cols 0..255
    lstm64_kernel<<<sgrid, 512, 0, stream>>>(
        A1b[1], 512, 16, nullptr, 0, 0, W1n, 512, b41, c1s, fused, 768, 0, Nn);

    // ---- GAT layer 1 (xl/xr in one launch) ----
    gemm16_dual_kernel<<<dim3(MT, 8), 256, 0, stream>>>(
        fused, 768, Wg0l, Wg0r, 256, g0_bl, g0_br, xlbuf, xrbuf, 512, Nn);
    gat_aggregate_kernel<<<dim3(Nn), 256, 0, stream>>>(
        xlbuf, xrbuf, g0_we, g0_att, g0_bias, offsets, src_sorted, ea_sorted,
        logit_buf, gbuf, 512, Nn);

    // ---- GAT layer 2 (output into fused cols 256..767) ----
    gemm16_dual_kernel<<<dim3(MT, 8), 256, 0, stream>>>(
        gbuf, 512, Wg1l, Wg1r, 512, g1_bl, g1_br, xlbuf, xrbuf, 512, Nn);
    gat_aggregate_kernel<<<dim3(Nn), 256, 0, stream>>>(
        xlbuf, xrbuf, g1_we, g1_att, g1_bias, offsets, src_sorted, ea_sorted,
        logit_buf, fused + 256, 768, Nn);

    // ---- fusion MLP ----
    gemm16_kernel<<<dim3(MT, 4), 256, 0, stream>>>(
        fused, 768, Wfc1, 768, fc1_b, nullptr, hfc1, 512, 1, Nn);
    fc2_kernel<<<dim3((Nn + 3) / 4), 256, 0, stream>>>(hfc1, fc2_w, fc2_b, out, Nn);
}

// Round 9
// 3560.428 us; speedup vs baseline: 1.2139x; 1.2139x over previous
//
#include <hip/hip_runtime.h>

#define DEV __device__ __forceinline__

typedef _Float16 f16;
typedef _Float16 f16x8 __attribute__((ext_vector_type(8)));
typedef _Float16 f16x2 __attribute__((ext_vector_type(2)));
typedef float f32x4 __attribute__((ext_vector_type(4)));

DEV float sigmoidf_(float x) { return 1.0f / (1.0f + __expf(-x)); }
DEV float tanhf2_(float x)   { return 1.0f - 2.0f / (__expf(2.0f * x) + 1.0f); }

// async global->LDS, 16B per lane. LDS dest = wave-uniform base + lane*16.
DEV void load_lds16(const void* g, void* l) {
    __builtin_amdgcn_global_load_lds(
        (const __attribute__((address_space(1))) char*)(const char*)g,
        (__attribute__((address_space(3))) char*)(unsigned int)(unsigned long long)(char*)l,
        16, 0, 0);
}

// LDS 16x32(f16) tile swizzle: chunk (row,ck) lives at physical slot
// ck ^ (row&3) ^ ((row>>2)&3). Loader permutes the GLOBAL chunk per lane;
// reader picks the matching physical slot (XOR involution).
DEV int swz(int row, int ck) { return ck ^ (row & 3) ^ ((row >> 2) & 3); }

// ---------------------------------------------------------------------------
// LSTM weight prep: Wt[1024][K] fp16, column-order chosen so that in the MFMA
// C-layout the 4 gates of a unit land in one lane's 4 j-fragments.
// dst row rd: T=rd>>7, p=rd&127, wh=(p>>6)&1, j=(p>>4)&3, c=p&15
//   unit u = T*32 + wh*16 + c ; gate g = j ; src row = g*256+u
// ---------------------------------------------------------------------------
__global__ void prep_w0_kernel(const float* __restrict__ wih,
                               const float* __restrict__ whh,
                               f16* __restrict__ dst) {   // [1024,288]
    int idx = blockIdx.x * 256 + threadIdx.x;
    if (idx >= 1024 * 288) return;
    int rd = idx / 288, k = idx - rd * 288;
    int T = rd >> 7, p = rd & 127;
    int u = T * 32 + ((p >> 6) & 1) * 16 + (p & 15);
    int g = (p >> 4) & 3;
    int src = g * 256 + u;
    float v;
    if (k < 16)        v = wih[src * 16 + k];
    else if (k < 272)  v = whh[src * 256 + (k - 16)];
    else               v = 0.f;
    dst[idx] = (f16)v;
}

__global__ void prep_w1_kernel(const float* __restrict__ wih,
                               const float* __restrict__ whh,
                               f16* __restrict__ dst) {   // [1024,512]
    int idx = blockIdx.x * 256 + threadIdx.x;
    if (idx >= 1024 * 512) return;
    int rd = idx >> 9, k = idx & 511;
    int T = rd >> 7, p = rd & 127;
    int u = T * 32 + ((p >> 6) & 1) * 16 + (p & 15);
    int g = (p >> 4) & 3;
    int src = g * 256 + u;
    float v = (k < 256) ? wih[src * 256 + k] : whh[src * 256 + (k - 256)];
    dst[idx] = (f16)v;
}

__global__ void prep_bias4_kernel(const float* __restrict__ bi,
                                  const float* __restrict__ bh,
                                  float* __restrict__ dst) {  // [1024] = [u*4+g]
    int idx = blockIdx.x * 256 + threadIdx.x;
    if (idx >= 1024) return;
    int u = idx >> 2, g = idx & 3;
    dst[idx] = bi[g * 256 + u] + bh[g * 256 + u];
}

// generic [K,N] fp32 -> [N,K] fp16 transpose
__global__ void prep_wt_kernel(const float* __restrict__ src, f16* __restrict__ dst,
                               int K, int N) {
    int idx = blockIdx.x * 256 + threadIdx.x;
    if (idx >= K * N) return;
    int n = idx / K, k = idx - n * K;
    dst[idx] = (f16)src[(size_t)k * N + n];
}

// x_seq[:,0,:16] -> A0buf0 cols 0..15
__global__ void prep_x0_kernel(const float* __restrict__ x_seq, f16* __restrict__ A0,
                               int Nn) {
    int idx = blockIdx.x * 256 + threadIdx.x;
    if (idx >= Nn * 16) return;
    int m = idx >> 4, f = idx & 15;
    A0[(size_t)m * 288 + f] = (f16)x_seq[(size_t)m * 960 + f];
}

// ---------------------------------------------------------------------------
// LSTM step core (f16 MFMA): gates = A @ Wt^T (+bias), cell update.
// A [Mpad,lda] fp16, Wt [1024,K] fp16, K%32==0. Tile 128x128, 4 waves 2x2.
// bx/by = logical tile coords (decoded from XCD-swizzled linear id).
// ---------------------------------------------------------------------------
DEV void lstm_step_core(
    f16* __restrict__ sA, f16* __restrict__ sB,
    int bx, int by,
    const f16* __restrict__ A, int lda, int K,
    const f16* __restrict__ Wt,
    const float* __restrict__ bias4,
    float* __restrict__ c_state,
    f16* __restrict__ hA, int ldhA, int offhA,
    f16* __restrict__ hB, int ldhB, int offhB,
    const float* __restrict__ xsrc, int tnext,
    int M)
{
    const int tid = threadIdx.x;
    const int w = tid >> 6, lane = tid & 63;
    const int m0 = bx * 128, n0 = by * 128;
    const int arow = lane >> 2;
    const int achk = swz(arow, lane & 3) * 8;
    const int frow = lane & 15, l4 = lane >> 4;
    const int fsl = swz(frow, l4) * 8;
    const int wr = (w >> 1) * 64, wc = (w & 1) * 64;

    f32x4 acc[4][4] = {};

    for (int k0 = 0; k0 < K; k0 += 32) {
        __syncthreads();
#pragma unroll
        for (int c = 0; c < 2; ++c) {
            int R = c * 64 + w * 16;
            load_lds16(A + (size_t)(m0 + R + arow) * lda + k0 + achk, sA + R * 32);
            load_lds16(Wt + (size_t)(n0 + R + arow) * K + k0 + achk, sB + R * 32);
        }
        __syncthreads();
        f16x8 af[4], bf[4];
#pragma unroll
        for (int i = 0; i < 4; ++i)
            af[i] = *(const f16x8*)&sA[(wr + i * 16 + frow) * 32 + fsl];
#pragma unroll
        for (int j = 0; j < 4; ++j)
            bf[j] = *(const f16x8*)&sB[(wc + j * 16 + frow) * 32 + fsl];
#pragma unroll
        for (int i = 0; i < 4; ++i)
#pragma unroll
            for (int j = 0; j < 4; ++j)
                acc[i][j] = __builtin_amdgcn_mfma_f32_16x16x32_f16(af[i], bf[j], acc[i][j], 0, 0, 0);
    }

    // epilogue: lane owns unit u, acc[i][j][r] = gate j of row m
    const int u = by * 32 + (w & 1) * 16 + (lane & 15);
    const float4 bb = *(const float4*)&bias4[u * 4];
    const int rbase = m0 + wr + (lane >> 4) * 4;
#pragma unroll
    for (int i = 0; i < 4; ++i) {
#pragma unroll
        for (int r = 0; r < 4; ++r) {
            int m = rbase + i * 16 + r;
            if (m < M) {
                float gi = sigmoidf_(acc[i][0][r] + bb.x);
                float gf = sigmoidf_(acc[i][1][r] + bb.y);
                float gg = tanhf2_(acc[i][2][r] + bb.z);
                float go = sigmoidf_(acc[i][3][r] + bb.w);
                float cold = c_state[(size_t)m * 256 + u];
                float cn = gf * cold + gi * gg;
                c_state[(size_t)m * 256 + u] = cn;
                f16 h = (f16)(go * tanhf2_(cn));
                hA[(size_t)m * ldhA + offhA + u] = h;
                if (hB) hB[(size_t)m * ldhB + offhB + u] = h;
            }
        }
    }
    // layer0 blocks (by==0) stage x_{t+1} into A0next cols 0..15
    if (xsrc && by == 0) {
        int row = tid >> 1, fb = (tid & 1) * 8;
        int m = m0 + row;
        if (m < M) {
            const float* xp = xsrc + (size_t)m * 960 + tnext * 16 + fb;
            f16* dp = hB + (size_t)m * ldhB + fb;
#pragma unroll
            for (int q = 0; q < 8; ++q) dp[q] = (f16)xp[q];
        }
    }
}

// solo (single-layer) LSTM step. Grid: mtPad8*8 linear, XCD-swizzled:
// l%8 = x%8 -> all 8 y-blocks of one x-tile land on one XCD (A/c L2 locality).
__global__ __launch_bounds__(256) void lstm_mfma_kernel(
    const f16* __restrict__ A, int lda, int K,
    const f16* __restrict__ Wt, const float* __restrict__ bias4,
    float* __restrict__ c_state,
    f16* __restrict__ hA, int ldhA, int offhA,
    f16* __restrict__ hB, int ldhB, int offhB,
    const float* __restrict__ xsrc, int tnext, int M, int mtiles)
{
    __shared__ __align__(16) f16 sA[128 * 32];
    __shared__ __align__(16) f16 sB[128 * 32];
    const int l = blockIdx.x;
    const int xcd = l & 7, q = l >> 3;
    const int y = q & 7, xhi = q >> 3;
    const int x = xhi * 8 + xcd;
    if (x >= mtiles) return;
    lstm_step_core(sA, sB, x, y, A, lda, K, Wt, bias4, c_state,
                   hA, ldhA, offhA, hB, ldhB, offhB, xsrc, tnext, M);
}

// merged: z=0 -> layer1(t), z=1 -> layer0(t+1). All 16 (y,z) blocks of one
// x-tile share an XCD.
__global__ __launch_bounds__(256) void lstm_dual_kernel(
    const f16* __restrict__ A1, const f16* __restrict__ W1t,
    const float* __restrict__ b41, float* __restrict__ c1,
    f16* __restrict__ h1A, int ldh1A, int offh1A,
    const f16* __restrict__ A0, const f16* __restrict__ W0t,
    const float* __restrict__ b40, float* __restrict__ c0,
    f16* __restrict__ h0A, int ldh0A, int offh0A,
    f16* __restrict__ h0B, int ldh0B, int offh0B,
    const float* __restrict__ xsrc, int tnext, int M, int mtiles)
{
    __shared__ __align__(16) f16 sA[128 * 32];
    __shared__ __align__(16) f16 sB[128 * 32];
    const int l = blockIdx.x;
    const int xcd = l & 7, q = l >> 3;
    const int yz = q & 15, xhi = q >> 4;
    const int x = xhi * 8 + xcd;
    if (x >= mtiles) return;
    const int y = yz & 7, z = yz >> 3;
    if (z == 0)
        lstm_step_core(sA, sB, x, y, A1, 512, 512, W1t, b41, c1,
                       h1A, ldh1A, offh1A, nullptr, 0, 0, nullptr, 0, M);
    else
        lstm_step_core(sA, sB, x, y, A0, 288, 288, W0t, b40, c0,
                       h0A, ldh0A, offh0A, h0B, ldh0B, offh0B, xsrc, tnext, M);
}

// ---------------------------------------------------------------------------
// Generic f16 MFMA GEMM: C = act(A[M,lda(K cols)] @ Bt[N,K]^T + bias)
// ---------------------------------------------------------------------------
__global__ __launch_bounds__(256) void gemm16_kernel(
    const f16* __restrict__ A, int lda,
    const f16* __restrict__ Bt, int K,
    const float* __restrict__ bias,
    f16* __restrict__ C16, float* __restrict__ C32, int ldc,
    int act, int M)
{
    __shared__ __align__(16) f16 sA[128 * 32];
    __shared__ __align__(16) f16 sB[128 * 32];
    const int tid = threadIdx.x;
    const int w = tid >> 6, lane = tid & 63;
    const int m0 = blockIdx.x * 128, n0 = blockIdx.y * 128;
    const int arow = lane >> 2;
    const int achk = swz(arow, lane & 3) * 8;
    const int frow = lane & 15, l4 = lane >> 4;
    const int fsl = swz(frow, l4) * 8;
    const int wr = (w >> 1) * 64, wcn = (w & 1) * 64;

    f32x4 acc[4][4] = {};

    for (int k0 = 0; k0 < K; k0 += 32) {
        __syncthreads();
#pragma unroll
        for (int c = 0; c < 2; ++c) {
            int R = c * 64 + w * 16;
            load_lds16(A + (size_t)(m0 + R + arow) * lda + k0 + achk, sA + R * 32);
            load_lds16(Bt + (size_t)(n0 + R + arow) * K + k0 + achk, sB + R * 32);
        }
        __syncthreads();
        f16x8 af[4], bf[4];
#pragma unroll
        for (int i = 0; i < 4; ++i)
            af[i] = *(const f16x8*)&sA[(wr + i * 16 + frow) * 32 + fsl];
#pragma unroll
        for (int j = 0; j < 4; ++j)
            bf[j] = *(const f16x8*)&sB[(wcn + j * 16 + frow) * 32 + fsl];
#pragma unroll
        for (int i = 0; i < 4; ++i)
#pragma unroll
            for (int j = 0; j < 4; ++j)
                acc[i][j] = __builtin_amdgcn_mfma_f32_16x16x32_f16(af[i], bf[j], acc[i][j], 0, 0, 0);
    }

    const int rbase = m0 + wr + (lane >> 4) * 4;
#pragma unroll
    for (int i = 0; i < 4; ++i) {
#pragma unroll
        for (int r = 0; r < 4; ++r) {
            int m = rbase + i * 16 + r;
            if (m >= M) continue;
#pragma unroll
            for (int j = 0; j < 4; ++j) {
                int n = n0 + wcn + j * 16 + (lane & 15);
                float v = acc[i][j][r] + bias[n];
                if (act == 1) v = fmaxf(v, 0.f);
                if (C16) C16[(size_t)m * ldc + n] = (f16)v;
                else     C32[(size_t)m * ldc + n] = v;
            }
        }
    }
}

// dual-B variant: y<4 -> (Btl,biasl,Cl), y>=4 -> (Btr,biasr,Cr). fp16 out.
__global__ __launch_bounds__(256) void gemm16_dual_kernel(
    const f16* __restrict__ A, int lda,
    const f16* __restrict__ Btl, const f16* __restrict__ Btr, int K,
    const float* __restrict__ biasl, const float* __restrict__ biasr,
    f16* __restrict__ Cl, f16* __restrict__ Cr, int ldc, int M)
{
    __shared__ __align__(16) f16 sA[128 * 32];
    __shared__ __align__(16) f16 sB[128 * 32];
    const int side = blockIdx.y >> 2;
    const f16* Bt = side ? Btr : Btl;
    const float* bias = side ? biasr : biasl;
    f16* C16 = side ? Cr : Cl;
    const int tid = threadIdx.x;
    const int w = tid >> 6, lane = tid & 63;
    const int m0 = blockIdx.x * 128, n0 = (blockIdx.y & 3) * 128;
    const int arow = lane >> 2;
    const int achk = swz(arow, lane & 3) * 8;
    const int frow = lane & 15, l4 = lane >> 4;
    const int fsl = swz(frow, l4) * 8;
    const int wr = (w >> 1) * 64, wcn = (w & 1) * 64;

    f32x4 acc[4][4] = {};

    for (int k0 = 0; k0 < K; k0 += 32) {
        __syncthreads();
#pragma unroll
        for (int c = 0; c < 2; ++c) {
            int R = c * 64 + w * 16;
            load_lds16(A + (size_t)(m0 + R + arow) * lda + k0 + achk, sA + R * 32);
            load_lds16(Bt + (size_t)(n0 + R + arow) * K + k0 + achk, sB + R * 32);
        }
        __syncthreads();
        f16x8 af[4], bf[4];
#pragma unroll
        for (int i = 0; i < 4; ++i)
            af[i] = *(const f16x8*)&sA[(wr + i * 16 + frow) * 32 + fsl];
#pragma unroll
        for (int j = 0; j < 4; ++j)
            bf[j] = *(const f16x8*)&sB[(wcn + j * 16 + frow) * 32 + fsl];
#pragma unroll
        for (int i = 0; i < 4; ++i)
#pragma unroll
            for (int j = 0; j < 4; ++j)
                acc[i][j] = __builtin_amdgcn_mfma_f32_16x16x32_f16(af[i], bf[j], acc[i][j], 0, 0, 0);
    }

    const int rbase = m0 + wr + (lane >> 4) * 4;
#pragma unroll
    for (int i = 0; i < 4; ++i) {
#pragma unroll
        for (int r = 0; r < 4; ++r) {
            int m = rbase + i * 16 + r;
            if (m >= M) continue;
#pragma unroll
            for (int j = 0; j < 4; ++j) {
                int n = n0 + wcn + j * 16 + (lane & 15);
                float v = acc[i][j][r] + bias[n];
                C16[(size_t)m * ldc + n] = (f16)v;
            }
        }
    }
}

// ---------------------------------------------------------------------------
// Edge preprocessing
// ---------------------------------------------------------------------------
__global__ void mean_sum_kernel(const float* __restrict__ a, int n, float* __restrict__ out) {
    __shared__ float s[256];
    float loc = 0.f;
    for (int i = blockIdx.x * 256 + threadIdx.x; i < n; i += gridDim.x * 256) loc += a[i];
    s[threadIdx.x] = loc;
    __syncthreads();
    for (int off = 128; off; off >>= 1) {
        if (threadIdx.x < off) s[threadIdx.x] += s[threadIdx.x + off];
        __syncthreads();
    }
    if (threadIdx.x == 0) atomicAdd(out, s[0]);
}

__global__ void hist_kernel(const int* __restrict__ ei, int Ne, int Nn,
                            int* __restrict__ counts) {
    int e = blockIdx.x * 256 + threadIdx.x;
    if (e >= Ne + Nn) return;
    int d = (e < Ne) ? ei[Ne + e] : (e - Ne);
    atomicAdd(&counts[d], 1);
}

__global__ void scan_kernel(const int* __restrict__ counts, int* __restrict__ offsets, int n) {
    __shared__ int s[256];
    int tid = threadIdx.x;
    int chunk = (n + 255) / 256;
    int b = tid * chunk;
    int loc = 0;
    for (int j = 0; j < chunk; ++j) { int i = b + j; if (i < n) loc += counts[i]; }
    s[tid] = loc;
    __syncthreads();
    for (int off = 1; off < 256; off <<= 1) {
        int v = (tid >= off) ? s[tid - off] : 0;
        __syncthreads();
        s[tid] += v;
        __syncthreads();
    }
    int run = (tid == 0) ? 0 : s[tid - 1];
    for (int j = 0; j < chunk; ++j) {
        int i = b + j;
        if (i < n) { offsets[i] = run; run += counts[i]; }
    }
    if (tid == 255) offsets[n] = run;
}

__global__ void scatter_kernel(const int* __restrict__ ei, const float* __restrict__ ea,
                               const float* __restrict__ sump, float inv_ne, int Ne, int Nn,
                               int* __restrict__ cursor, int* __restrict__ src_sorted,
                               float* __restrict__ ea_sorted) {
    int e = blockIdx.x * 256 + threadIdx.x;
    if (e >= Ne + Nn) return;
    int s, d; float a;
    if (e < Ne) { s = ei[e]; d = ei[Ne + e]; a = ea[e]; }
    else        { s = e - Ne; d = s; a = sump[0] * inv_ne; }
    int pos = atomicAdd(&cursor[d], 1);
    src_sorted[pos] = s;
    ea_sorted[pos] = a;
}

// ---------------------------------------------------------------------------
// GATv2 attention + aggregation (fp16 xl/xr), one block per dst node.
// ---------------------------------------------------------------------------
__global__ __launch_bounds__(256) void gat_aggregate_kernel(
    const f16* __restrict__ xl, const f16* __restrict__ xr,
    const float* __restrict__ we, const float* __restrict__ att,
    const float* __restrict__ bias,
    const int* __restrict__ offsets, const int* __restrict__ src_sorted,
    const float* __restrict__ ea_sorted,
    float* __restrict__ logit_buf, f16* __restrict__ out, int ldo, int N)
{
    __shared__ float s_xr[512], s_we[512], s_att[512];
    __shared__ float s_wmax[32], s_mx[8], s_den[8], s_rden[8];
    __shared__ float s_alpha[256];
    __shared__ int s_src[32];
    const int i = blockIdx.x;
    const int tid = threadIdx.x;
    s_xr[tid]       = (float)xr[(size_t)i * 512 + tid];
    s_xr[tid + 256] = (float)xr[(size_t)i * 512 + tid + 256];
    s_we[tid] = we[tid]; s_we[tid + 256] = we[tid + 256];
    s_att[tid] = att[tid]; s_att[tid + 256] = att[tid + 256];
    if (tid < 8) s_den[tid] = 0.f;
    __syncthreads();

    const int beg = offsets[i], end = offsets[i + 1];
    const int w = tid >> 6, lane = tid & 63;

    float wm[4] = {-1e30f, -1e30f, -1e30f, -1e30f};
    for (int e = beg + w; e < end; e += 4) {
        int s = src_sorted[e];
        float a = ea_sorted[e];
        float part[4];
#pragma unroll
        for (int cc = 0; cc < 4; ++cc) {
            int col = cc * 128 + lane * 2;
            f16x2 xv = *(const f16x2*)&xl[(size_t)s * 512 + col];
            float v0 = (float)xv.x + s_xr[col]     + a * s_we[col];
            float v1 = (float)xv.y + s_xr[col + 1] + a * s_we[col + 1];
            v0 = (v0 > 0.f) ? v0 : 0.2f * v0;
            v1 = (v1 > 0.f) ? v1 : 0.2f * v1;
            part[cc] = v0 * s_att[col] + v1 * s_att[col + 1];
        }
#pragma unroll
        for (int off = 16; off; off >>= 1)
#pragma unroll
            for (int cc = 0; cc < 4; ++cc) part[cc] += __shfl_xor(part[cc], off);
        if ((lane & 31) == 0) {
            int hb = lane >> 5;
#pragma unroll
            for (int cc = 0; cc < 4; ++cc) {
                logit_buf[(size_t)e * 8 + 2 * cc + hb] = part[cc];
                wm[cc] = fmaxf(wm[cc], part[cc]);
            }
        }
    }
    if ((lane & 31) == 0) {
        int hb = lane >> 5;
#pragma unroll
        for (int cc = 0; cc < 4; ++cc) s_wmax[w * 8 + 2 * cc + hb] = wm[cc];
    }
    __syncthreads();
    if (tid < 8) {
        float m = fmaxf(fmaxf(s_wmax[tid], s_wmax[8 + tid]),
                        fmaxf(s_wmax[16 + tid], s_wmax[24 + tid]));
        s_mx[tid] = m;
    }
    __syncthreads();

    for (int e = beg + tid; e < end; e += 256) {
#pragma unroll
        for (int h = 0; h < 8; ++h) {
            float ex = __expf(logit_buf[(size_t)e * 8 + h] - s_mx[h]);
            logit_buf[(size_t)e * 8 + h] = ex;
            atomicAdd(&s_den[h], ex);
        }
    }
    __syncthreads();
    if (tid < 8) s_rden[tid] = 1.f / s_den[tid];
    __syncthreads();

    float acc0 = 0.f, acc1 = 0.f;
    const int c2 = tid * 2, hh = tid >> 5;
    for (int chunk = beg; chunk < end; chunk += 32) {
        int cnt = min(32, end - chunk);
        if (tid < cnt) s_src[tid] = src_sorted[chunk + tid];
        int eo = tid >> 3, hq = tid & 7;
        if (eo < cnt) s_alpha[tid] = logit_buf[(size_t)(chunk + eo) * 8 + hq] * s_rden[hq];
        __syncthreads();
        for (int j = 0; j < cnt; ++j) {
            int s = s_src[j];
            f16x2 xv = *(const f16x2*)&xl[(size_t)s * 512 + c2];
            float al = s_alpha[j * 8 + hh];
            acc0 += al * (float)xv.x;
            acc1 += al * (float)xv.y;
        }
        __syncthreads();
    }
    float v0 = acc0 + bias[c2];
    float v1 = acc1 + bias[c2 + 1];
    v0 = (v0 > 0.f) ? v0 : __expf(v0) - 1.f;
    v1 = (v1 > 0.f) ? v1 : __expf(v1) - 1.f;
    f16x2 ov; ov.x = (f16)v0; ov.y = (f16)v1;
    *(f16x2*)&out[(size_t)i * ldo + c2] = ov;
}

// fc2: out[n] = H[n,:512] . w + b (fp32)
__global__ void fc2_kernel(const float* __restrict__ H, const float* __restrict__ w,
                           const float* __restrict__ b, float* __restrict__ out, int N) {
    int wv = threadIdx.x >> 6, lane = threadIdx.x & 63;
    int node = blockIdx.x * 4 + wv;
    if (node >= N) return;
    float s = 0.f;
#pragma unroll
    for (int j = 0; j < 8; ++j)
        s += H[(size_t)node * 512 + j * 64 + lane] * w[j * 64 + lane];
#pragma unroll
    for (int off = 32; off; off >>= 1) s += __shfl_xor(s, off, 64);
    if (lane == 0) out[node] = s + b[0];
}

// ---------------------------------------------------------------------------
extern "C" void kernel_launch(void* const* d_in, const int* in_sizes, int n_in,
                              void* d_out, int out_size, void* d_ws, size_t ws_size,
                              hipStream_t stream) {
    const float* x_seq     = (const float*)d_in[0];
    const int*   edge_index= (const int*)d_in[1];
    const float* edge_attr = (const float*)d_in[2];
    const float* w_ih0 = (const float*)d_in[3];
    const float* w_hh0 = (const float*)d_in[4];
    const float* b_ih0 = (const float*)d_in[5];
    const float* b_hh0 = (const float*)d_in[6];
    const float* w_ih1 = (const float*)d_in[7];
    const float* w_hh1 = (const float*)d_in[8];
    const float* b_ih1 = (const float*)d_in[9];
    const float* b_hh1 = (const float*)d_in[10];
    const float* g0_wl = (const float*)d_in[11];
    const float* g0_bl = (const float*)d_in[12];
    const float* g0_wr = (const float*)d_in[13];
    const float* g0_br = (const float*)d_in[14];
    const float* g0_we = (const float*)d_in[15];
    const float* g0_att= (const float*)d_in[16];
    const float* g0_bias=(const float*)d_in[17];
    const float* g1_wl = (const float*)d_in[18];
    const float* g1_bl = (const float*)d_in[19];
    const float* g1_wr = (const float*)d_in[20];
    const float* g1_br = (const float*)d_in[21];
    const float* g1_we = (const float*)d_in[22];
    const float* g1_att= (const float*)d_in[23];
    const float* g1_bias=(const float*)d_in[24];
    const float* fc1_w = (const float*)d_in[25];
    const float* fc1_b = (const float*)d_in[26];
    const float* fc2_w = (const float*)d_in[27];
    const float* fc2_b = (const float*)d_in[28];
    float* out = (float*)d_out;

    const int Nn = in_sizes[0] / (60 * 16);   // 10000
    const int Ne = in_sizes[1] / 2;           // 320000
    const int Etot = Ne + Nn;
    const int MT = (Nn + 127) / 128;          // 79
    const int Mpad = MT * 128;                // 10112
    const int MTpad8 = ((MT + 7) / 8) * 8;    // 80 (x padded for swizzle)

    size_t off = 0;
    auto alloc = [&](size_t bytes) -> void* {
        void* r = (char*)d_ws + off;
        off += (bytes + 255) & ~(size_t)255;
        return r;
    };
    f16* W0t   = (f16*)alloc((size_t)1024 * 288 * 2);
    f16* W1t   = (f16*)alloc((size_t)1024 * 512 * 2);
    float* b40 = (float*)alloc(1024 * 4);
    float* b41 = (float*)alloc(1024 * 4);
    f16* Wg0l  = (f16*)alloc((size_t)512 * 256 * 2);
    f16* Wg0r  = (f16*)alloc((size_t)512 * 256 * 2);
    f16* Wg1l  = (f16*)alloc((size_t)512 * 512 * 2);
    f16* Wg1r  = (f16*)alloc((size_t)512 * 512 * 2);
    f16* Wfc1  = (f16*)alloc((size_t)512 * 768 * 2);
    f16* A0b[2]; A0b[0] = (f16*)alloc((size_t)Mpad * 288 * 2);
                 A0b[1] = (f16*)alloc((size_t)Mpad * 288 * 2);
    f16* A1b[2]; A1b[0] = (f16*)alloc((size_t)Mpad * 512 * 2);
                 A1b[1] = (f16*)alloc((size_t)Mpad * 512 * 2);
    float* c0  = (float*)alloc((size_t)Mpad * 256 * 4);
    float* c1  = (float*)alloc((size_t)Mpad * 256 * 4);
    f16* fused = (f16*)alloc((size_t)Mpad * 768 * 2);
    f16* xlbuf = (f16*)alloc((size_t)Mpad * 512 * 2);
    f16* xrbuf = (f16*)alloc((size_t)Mpad * 512 * 2);
    f16* gbuf  = (f16*)alloc((size_t)Mpad * 512 * 2);
    float* hfc1= (float*)alloc((size_t)Mpad * 512 * 4);
    float* logit_buf = (float*)alloc((size_t)Etot * 8 * 4);
    int* counts  = (int*)alloc((size_t)Nn * 4);
    int* offsets = (int*)alloc((size_t)(Nn + 1) * 4);
    int* cursor  = (int*)alloc((size_t)Nn * 4);
    int* src_sorted = (int*)alloc((size_t)Etot * 4);
    float* ea_sorted = (float*)alloc((size_t)Etot * 4);
    float* meanp = (float*)alloc(256);

    // ---- weight / state prep ----
    prep_w0_kernel<<<dim3((1024 * 288 + 255) / 256), 256, 0, stream>>>(w_ih0, w_hh0, W0t);
    prep_w1_kernel<<<dim3((1024 * 512 + 255) / 256), 256, 0, stream>>>(w_ih1, w_hh1, W1t);
    prep_bias4_kernel<<<dim3(4), 256, 0, stream>>>(b_ih0, b_hh0, b40);
    prep_bias4_kernel<<<dim3(4), 256, 0, stream>>>(b_ih1, b_hh1, b41);
    prep_wt_kernel<<<dim3((256 * 512 + 255) / 256), 256, 0, stream>>>(g0_wl, Wg0l, 256, 512);
    prep_wt_kernel<<<dim3((256 * 512 + 255) / 256), 256, 0, stream>>>(g0_wr, Wg0r, 256, 512);
    prep_wt_kernel<<<dim3((512 * 512 + 255) / 256), 256, 0, stream>>>(g1_wl, Wg1l, 512, 512);
    prep_wt_kernel<<<dim3((512 * 512 + 255) / 256), 256, 0, stream>>>(g1_wr, Wg1r, 512, 512);
    prep_wt_kernel<<<dim3((768 * 512 + 255) / 256), 256, 0, stream>>>(fc1_w, Wfc1, 768, 512);
    hipMemsetAsync(A0b[0], 0, (size_t)Mpad * 288 * 2, stream);
    hipMemsetAsync(A1b[0], 0, (size_t)Mpad * 512 * 2, stream);
    hipMemsetAsync(c0, 0, (size_t)Mpad * 256 * 4, stream);
    hipMemsetAsync(c1, 0, (size_t)Mpad * 256 * 4, stream);
    prep_x0_kernel<<<dim3((Nn * 16 + 255) / 256), 256, 0, stream>>>(x_seq, A0b[0], Nn);

    // ---- edge prep (CSR by dst) ----
    hipMemsetAsync(meanp, 0, 4, stream);
    hipMemsetAsync(counts, 0, (size_t)Nn * 4, stream);
    mean_sum_kernel<<<dim3(256), 256, 0, stream>>>(edge_attr, Ne, meanp);
    hist_kernel<<<dim3((Etot + 255) / 256), 256, 0, stream>>>(edge_index, Ne, Nn, counts);
    scan_kernel<<<dim3(1), 256, 0, stream>>>(counts, offsets, Nn);
    hipMemcpyAsync(cursor, offsets, (size_t)Nn * 4, hipMemcpyDeviceToDevice, stream);
    scatter_kernel<<<dim3((Etot + 255) / 256), 256, 0, stream>>>(
        edge_index, edge_attr, meanp, 1.0f / (float)Ne, Ne, Nn, cursor, src_sorted, ea_sorted);

    // ---- 2-layer LSTM, 60 steps; L1(t) and L0(t+1) co-scheduled, XCD-swizzled ----
    const int solo_grid = MTpad8 * 8;    // 640
    const int dual_grid = MTpad8 * 16;   // 1280
    // L0(0)
    lstm_mfma_kernel<<<dim3(solo_grid), 256, 0, stream>>>(
        A0b[0], 288, 288, W0t, b40, c0,
        A1b[0], 512, 0,
        A0b[1], 288, 16,
        x_seq, 1, Nn, MT);
    // merged L1(k) + L0(k+1), k = 0..58
    for (int k = 0; k < 59; ++k) {
        lstm_dual_kernel<<<dim3(dual_grid), 256, 0, stream>>>(
            A1b[k & 1], W1t, b41, c1,
            A1b[(k + 1) & 1], 512, 256,
            A0b[(k + 1) & 1], W0t, b40, c0,
            A1b[(k + 1) & 1], 512, 0,
            A0b[k & 1], 288, 16,
            (k + 1 < 59) ? x_seq : nullptr, k + 2, Nn, MT);
    }
    // L1(59): write h1_59 (node) directly into fused cols 0..255
    lstm_mfma_kernel<<<dim3(solo_grid), 256, 0, stream>>>(
        A1b[1], 512, 512, W1t, b41, c1,
        fused, 768, 0,
        nullptr, 0, 0,
        nullptr, 0, Nn, MT);

    // ---- GAT layer 1 (xl/xr in one launch) ----
    gemm16_dual_kernel<<<dim3(MT, 8), 256, 0, stream>>>(
        fused, 768, Wg0l, Wg0r, 256, g0_bl, g0_br, xlbuf, xrbuf, 512, Nn);
    gat_aggregate_kernel<<<dim3(Nn), 256, 0, stream>>>(
        xlbuf, xrbuf, g0_we, g0_att, g0_bias, offsets, src_sorted, ea_sorted,
        logit_buf, gbuf, 512, Nn);

    // ---- GAT layer 2 (output into fused cols 256..767) ----
    gemm16_dual_kernel<<<dim3(MT, 8), 256, 0, stream>>>(
        gbuf, 512, Wg1l, Wg1r, 512, g1_bl, g1_br, xlbuf, xrbuf, 512, Nn);
    gat_aggregate_kernel<<<dim3(Nn), 256, 0, stream>>>(
        xlbuf, xrbuf, g1_we, g1_att, g1_bias, offsets, src_sorted, ea_sorted,
        logit_buf, fused + 256, 768, Nn);

    // ---- fusion MLP ----
    gemm16_kernel<<<dim3(MT, 4), 256, 0, stream>>>(
        fused, 768, Wfc1, 768, fc1_b, nullptr, hfc1, 512, 1, Nn);
    fc2_kernel<<<dim3((Nn + 3) / 4), 256, 0, stream>>>(hfc1, fc2_w, fc2_b, out, Nn);
}

// Round 10
// 3362.853 us; speedup vs baseline: 1.2853x; 1.0588x over previous
//
#include <hip/hip_runtime.h>

#define DEV __device__ __forceinline__

typedef _Float16 f16;
typedef _Float16 f16x8 __attribute__((ext_vector_type(8)));
typedef _Float16 f16x2 __attribute__((ext_vector_type(2)));
typedef float f32x4 __attribute__((ext_vector_type(4)));

DEV float sigmoidf_(float x) { return 1.0f / (1.0f + __expf(-x)); }
DEV float tanhf2_(float x)   { return 1.0f - 2.0f / (__expf(2.0f * x) + 1.0f); }

// async global->LDS, 16B per lane. LDS dest = wave-uniform base + lane*16.
DEV void load_lds16(const void* g, void* l) {
    __builtin_amdgcn_global_load_lds(
        (const __attribute__((address_space(1))) char*)(const char*)g,
        (__attribute__((address_space(3))) char*)(unsigned int)(unsigned long long)(char*)l,
        16, 0, 0);
}

// LDS 16x32(f16) tile swizzle: chunk (row,ck) lives at physical slot
// ck ^ (row&3) ^ ((row>>2)&3). Loader permutes the GLOBAL chunk per lane;
// reader picks the matching physical slot (XOR involution).
DEV int swz(int row, int ck) { return ck ^ (row & 3) ^ ((row >> 2) & 3); }

// ---------------------------------------------------------------------------
// LSTM weight prep: Wt[1024][K] fp16, column-order chosen so that in the MFMA
// C-layout the 4 gates of a unit land in one lane's 4 j-fragments.
// dst row rd: T=rd>>7, p=rd&127, wh=(p>>6)&1, j=(p>>4)&3, c=p&15
//   unit u = T*32 + wh*16 + c ; gate g = j ; src row = g*256+u
// W0t: [1024,320] — cols 0..15 x, 16..271 h0, 272..319 zero (K%64 pad)
// ---------------------------------------------------------------------------
__global__ void prep_w0_kernel(const float* __restrict__ wih,
                               const float* __restrict__ whh,
                               f16* __restrict__ dst) {   // [1024,320]
    int idx = blockIdx.x * 256 + threadIdx.x;
    if (idx >= 1024 * 320) return;
    int rd = idx / 320, k = idx - rd * 320;
    int T = rd >> 7, p = rd & 127;
    int u = T * 32 + ((p >> 6) & 1) * 16 + (p & 15);
    int g = (p >> 4) & 3;
    int src = g * 256 + u;
    float v;
    if (k < 16)        v = wih[src * 16 + k];
    else if (k < 272)  v = whh[src * 256 + (k - 16)];
    else               v = 0.f;
    dst[idx] = (f16)v;
}

__global__ void prep_w1_kernel(const float* __restrict__ wih,
                               const float* __restrict__ whh,
                               f16* __restrict__ dst) {   // [1024,512]
    int idx = blockIdx.x * 256 + threadIdx.x;
    if (idx >= 1024 * 512) return;
    int rd = idx >> 9, k = idx & 511;
    int T = rd >> 7, p = rd & 127;
    int u = T * 32 + ((p >> 6) & 1) * 16 + (p & 15);
    int g = (p >> 4) & 3;
    int src = g * 256 + u;
    float v = (k < 256) ? wih[src * 256 + k] : whh[src * 256 + (k - 256)];
    dst[idx] = (f16)v;
}

__global__ void prep_bias4_kernel(const float* __restrict__ bi,
                                  const float* __restrict__ bh,
                                  float* __restrict__ dst) {  // [1024] = [u*4+g]
    int idx = blockIdx.x * 256 + threadIdx.x;
    if (idx >= 1024) return;
    int u = idx >> 2, g = idx & 3;
    dst[idx] = bi[g * 256 + u] + bh[g * 256 + u];
}

// generic [K,N] fp32 -> [N,K] fp16 transpose
__global__ void prep_wt_kernel(const float* __restrict__ src, f16* __restrict__ dst,
                               int K, int N) {
    int idx = blockIdx.x * 256 + threadIdx.x;
    if (idx >= K * N) return;
    int n = idx / K, k = idx - n * K;
    dst[idx] = (f16)src[(size_t)k * N + n];
}

// x_seq[:,0,:16] -> A0buf0 cols 0..15 (lda 320)
__global__ void prep_x0_kernel(const float* __restrict__ x_seq, f16* __restrict__ A0,
                               int Nn) {
    int idx = blockIdx.x * 256 + threadIdx.x;
    if (idx >= Nn * 16) return;
    int m = idx >> 4, f = idx & 15;
    A0[(size_t)m * 320 + f] = (f16)x_seq[(size_t)m * 960 + f];
}

// ---------------------------------------------------------------------------
// LSTM step core (f16 MFMA): gates = A @ Wt^T (+bias), cell update.
// Tile 128x128, 4 waves 2x2, K-step 64 (2 chunks/drain), c prefetched
// before the K-loop. bx/by decoded from XCD-swizzled linear id.
// ---------------------------------------------------------------------------
DEV void lstm_step_core(
    f16* __restrict__ sA, f16* __restrict__ sB,   // [2*64*64] f16 each (8KB*2... 2 halves of 4096)
    int bx, int by,
    const f16* __restrict__ A, int lda, int K,
    const f16* __restrict__ Wt,
    const float* __restrict__ bias4,
    float* __restrict__ c_state,
    f16* __restrict__ hA, int ldhA, int offhA,
    f16* __restrict__ hB, int ldhB, int offhB,
    const float* __restrict__ xsrc, int tnext,
    int M)
{
    const int tid = threadIdx.x;
    const int w = tid >> 6, lane = tid & 63;
    const int m0 = bx * 128, n0 = by * 128;
    const int arow = lane >> 2;
    const int achk = swz(arow, lane & 3) * 8;
    const int frow = lane & 15, l4 = lane >> 4;
    const int fsl = swz(frow, l4) * 8;
    const int wr = (w >> 1) * 64, wc = (w & 1) * 64;

    // prefetch c-state (epilogue inputs) — K-loop covers the latency.
    // Loads are within padded workspace rows; stores remain guarded.
    const int u = by * 32 + (w & 1) * 16 + (lane & 15);
    const int rbase = m0 + wr + (lane >> 4) * 4;
    float cold[4][4];
#pragma unroll
    for (int i = 0; i < 4; ++i)
#pragma unroll
        for (int r = 0; r < 4; ++r)
            cold[i][r] = c_state[(size_t)(rbase + i * 16 + r) * 256 + u];

    f32x4 acc[4][4] = {};

    for (int k0 = 0; k0 < K; k0 += 64) {
        __syncthreads();
#pragma unroll
        for (int half = 0; half < 2; ++half) {
#pragma unroll
            for (int c = 0; c < 2; ++c) {
                int R = c * 64 + w * 16;
                load_lds16(A + (size_t)(m0 + R + arow) * lda + k0 + half * 32 + achk,
                           sA + half * 4096 + R * 32);
                load_lds16(Wt + (size_t)(n0 + R + arow) * K + k0 + half * 32 + achk,
                           sB + half * 4096 + R * 32);
            }
        }
        __syncthreads();
#pragma unroll
        for (int half = 0; half < 2; ++half) {
            f16x8 af[4], bf[4];
#pragma unroll
            for (int i = 0; i < 4; ++i)
                af[i] = *(const f16x8*)&sA[half * 4096 + (wr + i * 16 + frow) * 32 + fsl];
#pragma unroll
            for (int j = 0; j < 4; ++j)
                bf[j] = *(const f16x8*)&sB[half * 4096 + (wc + j * 16 + frow) * 32 + fsl];
#pragma unroll
            for (int i = 0; i < 4; ++i)
#pragma unroll
                for (int j = 0; j < 4; ++j)
                    acc[i][j] = __builtin_amdgcn_mfma_f32_16x16x32_f16(af[i], bf[j], acc[i][j], 0, 0, 0);
        }
    }

    // epilogue: lane owns unit u, acc[i][j][r] = gate j of row m
    const float4 bb = *(const float4*)&bias4[u * 4];
#pragma unroll
    for (int i = 0; i < 4; ++i) {
#pragma unroll
        for (int r = 0; r < 4; ++r) {
            int m = rbase + i * 16 + r;
            if (m < M) {
                float gi = sigmoidf_(acc[i][0][r] + bb.x);
                float gf = sigmoidf_(acc[i][1][r] + bb.y);
                float gg = tanhf2_(acc[i][2][r] + bb.z);
                float go = sigmoidf_(acc[i][3][r] + bb.w);
                float cn = gf * cold[i][r] + gi * gg;
                c_state[(size_t)m * 256 + u] = cn;
                f16 h = (f16)(go * tanhf2_(cn));
                hA[(size_t)m * ldhA + offhA + u] = h;
                if (hB) hB[(size_t)m * ldhB + offhB + u] = h;
            }
        }
    }
    // layer0 blocks (by==0) stage x_{t+1} into A0next cols 0..15
    if (xsrc && by == 0) {
        int row = tid >> 1, fb = (tid & 1) * 8;
        int m = m0 + row;
        if (m < M) {
            const float* xp = xsrc + (size_t)m * 960 + tnext * 16 + fb;
            f16* dp = hB + (size_t)m * ldhB + fb;
#pragma unroll
            for (int q = 0; q < 8; ++q) dp[q] = (f16)xp[q];
        }
    }
}

// solo (single-layer) LSTM step. Grid: mtPad8*8 linear, XCD-swizzled:
// l%8 = x%8 -> all 8 y-blocks of one x-tile land on one XCD (A/c L2 locality).
__global__ __launch_bounds__(256) void lstm_mfma_kernel(
    const f16* __restrict__ A, int lda, int K,
    const f16* __restrict__ Wt, const float* __restrict__ bias4,
    float* __restrict__ c_state,
    f16* __restrict__ hA, int ldhA, int offhA,
    f16* __restrict__ hB, int ldhB, int offhB,
    const float* __restrict__ xsrc, int tnext, int M, int mtiles)
{
    __shared__ __align__(16) f16 sA[2 * 4096];
    __shared__ __align__(16) f16 sB[2 * 4096];
    const int l = blockIdx.x;
    const int xcd = l & 7, q = l >> 3;
    const int y = q & 7, xhi = q >> 3;
    const int x = xhi * 8 + xcd;
    if (x >= mtiles) return;
    lstm_step_core(sA, sB, x, y, A, lda, K, Wt, bias4, c_state,
                   hA, ldhA, offhA, hB, ldhB, offhB, xsrc, tnext, M);
}

// merged: z=0 -> layer1(t), z=1 -> layer0(t+1). All 16 (y,z) blocks of one
// x-tile share an XCD.
__global__ __launch_bounds__(256) void lstm_dual_kernel(
    const f16* __restrict__ A1, const f16* __restrict__ W1t,
    const float* __restrict__ b41, float* __restrict__ c1,
    f16* __restrict__ h1A, int ldh1A, int offh1A,
    const f16* __restrict__ A0, const f16* __restrict__ W0t,
    const float* __restrict__ b40, float* __restrict__ c0,
    f16* __restrict__ h0A, int ldh0A, int offh0A,
    f16* __restrict__ h0B, int ldh0B, int offh0B,
    const float* __restrict__ xsrc, int tnext, int M, int mtiles)
{
    __shared__ __align__(16) f16 sA[2 * 4096];
    __shared__ __align__(16) f16 sB[2 * 4096];
    const int l = blockIdx.x;
    const int xcd = l & 7, q = l >> 3;
    const int yz = q & 15, xhi = q >> 4;
    const int x = xhi * 8 + xcd;
    if (x >= mtiles) return;
    const int y = yz & 7, z = yz >> 3;
    if (z == 0)
        lstm_step_core(sA, sB, x, y, A1, 512, 512, W1t, b41, c1,
                       h1A, ldh1A, offh1A, nullptr, 0, 0, nullptr, 0, M);
    else
        lstm_step_core(sA, sB, x, y, A0, 320, 320, W0t, b40, c0,
                       h0A, ldh0A, offh0A, h0B, ldh0B, offh0B, xsrc, tnext, M);
}

// ---------------------------------------------------------------------------
// Generic f16 MFMA GEMM: C = act(A[M,lda(K cols)] @ Bt[N,K]^T + bias)
// ---------------------------------------------------------------------------
__global__ __launch_bounds__(256) void gemm16_kernel(
    const f16* __restrict__ A, int lda,
    const f16* __restrict__ Bt, int K,
    const float* __restrict__ bias,
    f16* __restrict__ C16, float* __restrict__ C32, int ldc,
    int act, int M)
{
    __shared__ __align__(16) f16 sA[128 * 32];
    __shared__ __align__(16) f16 sB[128 * 32];
    const int tid = threadIdx.x;
    const int w = tid >> 6, lane = tid & 63;
    const int m0 = blockIdx.x * 128, n0 = blockIdx.y * 128;
    const int arow = lane >> 2;
    const int achk = swz(arow, lane & 3) * 8;
    const int frow = lane & 15, l4 = lane >> 4;
    const int fsl = swz(frow, l4) * 8;
    const int wr = (w >> 1) * 64, wcn = (w & 1) * 64;

    f32x4 acc[4][4] = {};

    for (int k0 = 0; k0 < K; k0 += 32) {
        __syncthreads();
#pragma unroll
        for (int c = 0; c < 2; ++c) {
            int R = c * 64 + w * 16;
            load_lds16(A + (size_t)(m0 + R + arow) * lda + k0 + achk, sA + R * 32);
            load_lds16(Bt + (size_t)(n0 + R + arow) * K + k0 + achk, sB + R * 32);
        }
        __syncthreads();
        f16x8 af[4], bf[4];
#pragma unroll
        for (int i = 0; i < 4; ++i)
            af[i] = *(const f16x8*)&sA[(wr + i * 16 + frow) * 32 + fsl];
#pragma unroll
        for (int j = 0; j < 4; ++j)
            bf[j] = *(const f16x8*)&sB[(wcn + j * 16 + frow) * 32 + fsl];
#pragma unroll
        for (int i = 0; i < 4; ++i)
#pragma unroll
            for (int j = 0; j < 4; ++j)
                acc[i][j] = __builtin_amdgcn_mfma_f32_16x16x32_f16(af[i], bf[j], acc[i][j], 0, 0, 0);
    }

    const int rbase = m0 + wr + (lane >> 4) * 4;
#pragma unroll
    for (int i = 0; i < 4; ++i) {
#pragma unroll
        for (int r = 0; r < 4; ++r) {
            int m = rbase + i * 16 + r;
            if (m >= M) continue;
#pragma unroll
            for (int j = 0; j < 4; ++j) {
                int n = n0 + wcn + j * 16 + (lane & 15);
                float v = acc[i][j][r] + bias[n];
                if (act == 1) v = fmaxf(v, 0.f);
                if (C16) C16[(size_t)m * ldc + n] = (f16)v;
                else     C32[(size_t)m * ldc + n] = v;
            }
        }
    }
}

// dual-B variant: y<4 -> (Btl,biasl,Cl), y>=4 -> (Btr,biasr,Cr). fp16 out.
__global__ __launch_bounds__(256) void gemm16_dual_kernel(
    const f16* __restrict__ A, int lda,
    const f16* __restrict__ Btl, const f16* __restrict__ Btr, int K,
    const float* __restrict__ biasl, const float* __restrict__ biasr,
    f16* __restrict__ Cl, f16* __restrict__ Cr, int ldc, int M)
{
    __shared__ __align__(16) f16 sA[128 * 32];
    __shared__ __align__(16) f16 sB[128 * 32];
    const int side = blockIdx.y >> 2;
    const f16* Bt = side ? Btr : Btl;
    const float* bias = side ? biasr : biasl;
    f16* C16 = side ? Cr : Cl;
    const int tid = threadIdx.x;
    const int w = tid >> 6, lane = tid & 63;
    const int m0 = blockIdx.x * 128, n0 = (blockIdx.y & 3) * 128;
    const int arow = lane >> 2;
    const int achk = swz(arow, lane & 3) * 8;
    const int frow = lane & 15, l4 = lane >> 4;
    const int fsl = swz(frow, l4) * 8;
    const int wr = (w >> 1) * 64, wcn = (w & 1) * 64;

    f32x4 acc[4][4] = {};

    for (int k0 = 0; k0 < K; k0 += 32) {
        __syncthreads();
#pragma unroll
        for (int c = 0; c < 2; ++c) {
            int R = c * 64 + w * 16;
            load_lds16(A + (size_t)(m0 + R + arow) * lda + k0 + achk, sA + R * 32);
            load_lds16(Bt + (size_t)(n0 + R + arow) * K + k0 + achk, sB + R * 32);
        }
        __syncthreads();
        f16x8 af[4], bf[4];
#pragma unroll
        for (int i = 0; i < 4; ++i)
            af[i] = *(const f16x8*)&sA[(wr + i * 16 + frow) * 32 + fsl];
#pragma unroll
        for (int j = 0; j < 4; ++j)
            bf[j] = *(const f16x8*)&sB[(wcn + j * 16 + frow) * 32 + fsl];
#pragma unroll
        for (int i = 0; i < 4; ++i)
#pragma unroll
            for (int j = 0; j < 4; ++j)
                acc[i][j] = __builtin_amdgcn_mfma_f32_16x16x32_f16(af[i], bf[j], acc[i][j], 0, 0, 0);
    }

    const int rbase = m0 + wr + (lane >> 4) * 4;
#pragma unroll
    for (int i = 0; i < 4; ++i) {
#pragma unroll
        for (int r = 0; r < 4; ++r) {
            int m = rbase + i * 16 + r;
            if (m >= M) continue;
#pragma unroll
            for (int j = 0; j < 4; ++j) {
                int n = n0 + wcn + j * 16 + (lane & 15);
                float v = acc[i][j][r] + bias[n];
                C16[(size_t)m * ldc + n] = (f16)v;
            }
        }
    }
}

// ---------------------------------------------------------------------------
// Edge preprocessing
// ---------------------------------------------------------------------------
__global__ void mean_sum_kernel(const float* __restrict__ a, int n, float* __restrict__ out) {
    __shared__ float s[256];
    float loc = 0.f;
    for (int i = blockIdx.x * 256 + threadIdx.x; i < n; i += gridDim.x * 256) loc += a[i];
    s[threadIdx.x] = loc;
    __syncthreads();
    for (int off = 128; off; off >>= 1) {
        if (threadIdx.x < off) s[threadIdx.x] += s[threadIdx.x + off];
        __syncthreads();
    }
    if (threadIdx.x == 0) atomicAdd(out, s[0]);
}

__global__ void hist_kernel(const int* __restrict__ ei, int Ne, int Nn,
                            int* __restrict__ counts) {
    int e = blockIdx.x * 256 + threadIdx.x;
    if (e >= Ne + Nn) return;
    int d = (e < Ne) ? ei[Ne + e] : (e - Ne);
    atomicAdd(&counts[d], 1);
}

__global__ void scan_kernel(const int* __restrict__ counts, int* __restrict__ offsets, int n) {
    __shared__ int s[256];
    int tid = threadIdx.x;
    int chunk = (n + 255) / 256;
    int b = tid * chunk;
    int loc = 0;
    for (int j = 0; j < chunk; ++j) { int i = b + j; if (i < n) loc += counts[i]; }
    s[tid] = loc;
    __syncthreads();
    for (int off = 1; off < 256; off <<= 1) {
        int v = (tid >= off) ? s[tid - off] : 0;
        __syncthreads();
        s[tid] += v;
        __syncthreads();
    }
    int run = (tid == 0) ? 0 : s[tid - 1];
    for (int j = 0; j < chunk; ++j) {
        int i = b + j;
        if (i < n) { offsets[i] = run; run += counts[i]; }
    }
    if (tid == 255) offsets[n] = run;
}

__global__ void scatter_kernel(const int* __restrict__ ei, const float* __restrict__ ea,
                               const float* __restrict__ sump, float inv_ne, int Ne, int Nn,
                               int* __restrict__ cursor, int* __restrict__ src_sorted,
                               float* __restrict__ ea_sorted) {
    int e = blockIdx.x * 256 + threadIdx.x;
    if (e >= Ne + Nn) return;
    int s, d; float a;
    if (e < Ne) { s = ei[e]; d = ei[Ne + e]; a = ea[e]; }
    else        { s = e - Ne; d = s; a = sump[0] * inv_ne; }
    int pos = atomicAdd(&cursor[d], 1);
    src_sorted[pos] = s;
    ea_sorted[pos] = a;
}

// ---------------------------------------------------------------------------
// GATv2 attention + aggregation (fp16 xl/xr), one block per dst node.
// ---------------------------------------------------------------------------
__global__ __launch_bounds__(256) void gat_aggregate_kernel(
    const f16* __restrict__ xl, const f16* __restrict__ xr,
    const float* __restrict__ we, const float* __restrict__ att,
    const float* __restrict__ bias,
    const int* __restrict__ offsets, const int* __restrict__ src_sorted,
    const float* __restrict__ ea_sorted,
    float* __restrict__ logit_buf, f16* __restrict__ out, int ldo, int N)
{
    __shared__ float s_xr[512], s_we[512], s_att[512];
    __shared__ float s_wmax[32], s_mx[8], s_den[8], s_rden[8];
    __shared__ float s_alpha[256];
    __shared__ int s_src[32];
    const int i = blockIdx.x;
    const int tid = threadIdx.x;
    s_xr[tid]       = (float)xr[(size_t)i * 512 + tid];
    s_xr[tid + 256] = (float)xr[(size_t)i * 512 + tid + 256];
    s_we[tid] = we[tid]; s_we[tid + 256] = we[tid + 256];
    s_att[tid] = att[tid]; s_att[tid + 256] = att[tid + 256];
    if (tid < 8) s_den[tid] = 0.f;
    __syncthreads();

    const int beg = offsets[i], end = offsets[i + 1];
    const int w = tid >> 6, lane = tid & 63;

    float wm[4] = {-1e30f, -1e30f, -1e30f, -1e30f};
    for (int e = beg + w; e < end; e += 4) {
        int s = src_sorted[e];
        float a = ea_sorted[e];
        float part[4];
#pragma unroll
        for (int cc = 0; cc < 4; ++cc) {
            int col = cc * 128 + lane * 2;
            f16x2 xv = *(const f16x2*)&xl[(size_t)s * 512 + col];
            float v0 = (float)xv.x + s_xr[col]     + a * s_we[col];
            float v1 = (float)xv.y + s_xr[col + 1] + a * s_we[col + 1];
            v0 = (v0 > 0.f) ? v0 : 0.2f * v0;
            v1 = (v1 > 0.f) ? v1 : 0.2f * v1;
            part[cc] = v0 * s_att[col] + v1 * s_att[col + 1];
        }
#pragma unroll
        for (int off = 16; off; off >>= 1)
#pragma unroll
            for (int cc = 0; cc < 4; ++cc) part[cc] += __shfl_xor(part[cc], off);
        if ((lane & 31) == 0) {
            int hb = lane >> 5;
#pragma unroll
            for (int cc = 0; cc < 4; ++cc) {
                logit_buf[(size_t)e * 8 + 2 * cc + hb] = part[cc];
                wm[cc] = fmaxf(wm[cc], part[cc]);
            }
        }
    }
    if ((lane & 31) == 0) {
        int hb = lane >> 5;
#pragma unroll
        for (int cc = 0; cc < 4; ++cc) s_wmax[w * 8 + 2 * cc + hb] = wm[cc];
    }
    __syncthreads();
    if (tid < 8) {
        float m = fmaxf(fmaxf(s_wmax[tid], s_wmax[8 + tid]),
                        fmaxf(s_wmax[16 + tid], s_wmax[24 + tid]));
        s_mx[tid] = m;
    }
    __syncthreads();

    for (int e = beg + tid; e < end; e += 256) {
#pragma unroll
        for (int h = 0; h < 8; ++h) {
            float ex = __expf(logit_buf[(size_t)e * 8 + h] - s_mx[h]);
            logit_buf[(size_t)e * 8 + h] = ex;
            atomicAdd(&s_den[h], ex);
        }
    }
    __syncthreads();
    if (tid < 8) s_rden[tid] = 1.f / s_den[tid];
    __syncthreads();

    float acc0 = 0.f, acc1 = 0.f;
    const int c2 = tid * 2, hh = tid >> 5;
    for (int chunk = beg; chunk < end; chunk += 32) {
        int cnt = min(32, end - chunk);
        if (tid < cnt) s_src[tid] = src_sorted[chunk + tid];
        int eo = tid >> 3, hq = tid & 7;
        if (eo < cnt) s_alpha[tid] = logit_buf[(size_t)(chunk + eo) * 8 + hq] * s_rden[hq];
        __syncthreads();
        for (int j = 0; j < cnt; ++j) {
            int s = s_src[j];
            f16x2 xv = *(const f16x2*)&xl[(size_t)s * 512 + c2];
            float al = s_alpha[j * 8 + hh];
            acc0 += al * (float)xv.x;
            acc1 += al * (float)xv.y;
        }
        __syncthreads();
    }
    float v0 = acc0 + bias[c2];
    float v1 = acc1 + bias[c2 + 1];
    v0 = (v0 > 0.f) ? v0 : __expf(v0) - 1.f;
    v1 = (v1 > 0.f) ? v1 : __expf(v1) - 1.f;
    f16x2 ov; ov.x = (f16)v0; ov.y = (f16)v1;
    *(f16x2*)&out[(size_t)i * ldo + c2] = ov;
}

// fc2: out[n] = H[n,:512] . w + b (fp32)
__global__ void fc2_kernel(const float* __restrict__ H, const float* __restrict__ w,
                           const float* __restrict__ b, float* __restrict__ out, int N) {
    int wv = threadIdx.x >> 6, lane = threadIdx.x & 63;
    int node = blockIdx.x * 4 + wv;
    if (node >= N) return;
    float s = 0.f;
#pragma unroll
    for (int j = 0; j < 8; ++j)
        s += H[(size_t)node * 512 + j * 64 + lane] * w[j * 64 + lane];
#pragma unroll
    for (int off = 32; off; off >>= 1) s += __shfl_xor(s, off, 64);
    if (lane == 0) out[node] = s + b[0];
}

// ---------------------------------------------------------------------------
extern "C" void kernel_launch(void* const* d_in, const int* in_sizes, int n_in,
                              void* d_out, int out_size, void* d_ws, size_t ws_size,
                              hipStream_t stream) {
    const float* x_seq     = (const float*)d_in[0];
    const int*   edge_index= (const int*)d_in[1];
    const float* edge_attr = (const float*)d_in[2];
    const float* w_ih0 = (const float*)d_in[3];
    const float* w_hh0 = (const float*)d_in[4];
    const float* b_ih0 = (const float*)d_in[5];
    const float* b_hh0 = (const float*)d_in[6];
    const float* w_ih1 = (const float*)d_in[7];
    const float* w_hh1 = (const float*)d_in[8];
    const float* b_ih1 = (const float*)d_in[9];
    const float* b_hh1 = (const float*)d_in[10];
    const float* g0_wl = (const float*)d_in[11];
    const float* g0_bl = (const float*)d_in[12];
    const float* g0_wr = (const float*)d_in[13];
    const float* g0_br = (const float*)d_in[14];
    const float* g0_we = (const float*)d_in[15];
    const float* g0_att= (const float*)d_in[16];
    const float* g0_bias=(const float*)d_in[17];
    const float* g1_wl = (const float*)d_in[18];
    const float* g1_bl = (const float*)d_in[19];
    const float* g1_wr = (const float*)d_in[20];
    const float* g1_br = (const float*)d_in[21];
    const float* g1_we = (const float*)d_in[22];
    const float* g1_att= (const float*)d_in[23];
    const float* g1_bias=(const float*)d_in[24];
    const float* fc1_w = (const float*)d_in[25];
    const float* fc1_b = (const float*)d_in[26];
    const float* fc2_w = (const float*)d_in[27];
    const float* fc2_b = (const float*)d_in[28];
    float* out = (float*)d_out;

    const int Nn = in_sizes[0] / (60 * 16);   // 10000
    const int Ne = in_sizes[1] / 2;           // 320000
    const int Etot = Ne + Nn;
    const int MT = (Nn + 127) / 128;          // 79
    const int Mpad = MT * 128;                // 10112
    const int MTpad8 = ((MT + 7) / 8) * 8;    // 80 (x padded for swizzle)

    size_t off = 0;
    auto alloc = [&](size_t bytes) -> void* {
        void* r = (char*)d_ws + off;
        off += (bytes + 255) & ~(size_t)255;
        return r;
    };
    f16* W0t   = (f16*)alloc((size_t)1024 * 320 * 2);
    f16* W1t   = (f16*)alloc((size_t)1024 * 512 * 2);
    float* b40 = (float*)alloc(1024 * 4);
    float* b41 = (float*)alloc(1024 * 4);
    f16* Wg0l  = (f16*)alloc((size_t)512 * 256 * 2);
    f16* Wg0r  = (f16*)alloc((size_t)512 * 256 * 2);
    f16* Wg1l  = (f16*)alloc((size_t)512 * 512 * 2);
    f16* Wg1r  = (f16*)alloc((size_t)512 * 512 * 2);
    f16* Wfc1  = (f16*)alloc((size_t)512 * 768 * 2);
    f16* A0b[2]; A0b[0] = (f16*)alloc((size_t)Mpad * 320 * 2);
                 A0b[1] = (f16*)alloc((size_t)Mpad * 320 * 2);
    f16* A1b[2]; A1b[0] = (f16*)alloc((size_t)Mpad * 512 * 2);
                 A1b[1] = (f16*)alloc((size_t)Mpad * 512 * 2);
    float* c0  = (float*)alloc((size_t)Mpad * 256 * 4);
    float* c1  = (float*)alloc((size_t)Mpad * 256 * 4);
    f16* fused = (f16*)alloc((size_t)Mpad * 768 * 2);
    f16* xlbuf = (f16*)alloc((size_t)Mpad * 512 * 2);
    f16* xrbuf = (f16*)alloc((size_t)Mpad * 512 * 2);
    f16* gbuf  = (f16*)alloc((size_t)Mpad * 512 * 2);
    float* hfc1= (float*)alloc((size_t)Mpad * 512 * 4);
    float* logit_buf = (float*)alloc((size_t)Etot * 8 * 4);
    int* counts  = (int*)alloc((size_t)Nn * 4);
    int* offsets = (int*)alloc((size_t)(Nn + 1) * 4);
    int* cursor  = (int*)alloc((size_t)Nn * 4);
    int* src_sorted = (int*)alloc((size_t)Etot * 4);
    float* ea_sorted = (float*)alloc((size_t)Etot * 4);
    float* meanp = (float*)alloc(256);

    // ---- weight / state prep ----
    prep_w0_kernel<<<dim3((1024 * 320 + 255) / 256), 256, 0, stream>>>(w_ih0, w_hh0, W0t);
    prep_w1_kernel<<<dim3((1024 * 512 + 255) / 256), 256, 0, stream>>>(w_ih1, w_hh1, W1t);
    prep_bias4_kernel<<<dim3(4), 256, 0, stream>>>(b_ih0, b_hh0, b40);
    prep_bias4_kernel<<<dim3(4), 256, 0, stream>>>(b_ih1, b_hh1, b41);
    prep_wt_kernel<<<dim3((256 * 512 + 255) / 256), 256, 0, stream>>>(g0_wl, Wg0l, 256, 512);
    prep_wt_kernel<<<dim3((256 * 512 + 255) / 256), 256, 0, stream>>>(g0_wr, Wg0r, 256, 512);
    prep_wt_kernel<<<dim3((512 * 512 + 255) / 256), 256, 0, stream>>>(g1_wl, Wg1l, 512, 512);
    prep_wt_kernel<<<dim3((512 * 512 + 255) / 256), 256, 0, stream>>>(g1_wr, Wg1r, 512, 512);
    prep_wt_kernel<<<dim3((768 * 512 + 255) / 256), 256, 0, stream>>>(fc1_w, Wfc1, 768, 512);
    hipMemsetAsync(A0b[0], 0, (size_t)Mpad * 320 * 2, stream);
    hipMemsetAsync(A0b[1], 0, (size_t)Mpad * 320 * 2, stream);
    hipMemsetAsync(A1b[0], 0, (size_t)Mpad * 512 * 2, stream);
    hipMemsetAsync(c0, 0, (size_t)Mpad * 256 * 4, stream);
    hipMemsetAsync(c1, 0, (size_t)Mpad * 256 * 4, stream);
    prep_x0_kernel<<<dim3((Nn * 16 + 255) / 256), 256, 0, stream>>>(x_seq, A0b[0], Nn);

    // ---- edge prep (CSR by dst) ----
    hipMemsetAsync(meanp, 0, 4, stream);
    hipMemsetAsync(counts, 0, (size_t)Nn * 4, stream);
    mean_sum_kernel<<<dim3(256), 256, 0, stream>>>(edge_attr, Ne, meanp);
    hist_kernel<<<dim3((Etot + 255) / 256), 256, 0, stream>>>(edge_index, Ne, Nn, counts);
    scan_kernel<<<dim3(1), 256, 0, stream>>>(counts, offsets, Nn);
    hipMemcpyAsync(cursor, offsets, (size_t)Nn * 4, hipMemcpyDeviceToDevice, stream);
    scatter_kernel<<<dim3((Etot + 255) / 256), 256, 0, stream>>>(
        edge_index, edge_attr, meanp, 1.0f / (float)Ne, Ne, Nn, cursor, src_sorted, ea_sorted);

    // ---- 2-layer LSTM, 60 steps; L1(t) and L0(t+1) co-scheduled, XCD-swizzled ----
    const int solo_grid = MTpad8 * 8;    // 640
    const int dual_grid = MTpad8 * 16;   // 1280
    // L0(0)
    lstm_mfma_kernel<<<dim3(solo_grid), 256, 0, stream>>>(
        A0b[0], 320, 320, W0t, b40, c0,
        A1b[0], 512, 0,
        A0b[1], 320, 16,
        x_seq, 1, Nn, MT);
    // merged L1(k) + L0(k+1), k = 0..58
    for (int k = 0; k < 59; ++k) {
        lstm_dual_kernel<<<dim3(dual_grid), 256, 0, stream>>>(
            A1b[k & 1], W1t, b41, c1,
            A1b[(k + 1) & 1], 512, 256,
            A0b[(k + 1) & 1], W0t, b40, c0,
            A1b[(k + 1) & 1], 512, 0,
            A0b[k & 1], 320, 16,
            (k + 1 < 59) ? x_seq : nullptr, k + 2, Nn, MT);
    }
    // L1(59): write h1_59 (node) directly into fused cols 0..255
    lstm_mfma_kernel<<<dim3(solo_grid), 256, 0, stream>>>(
        A1b[1], 512, 512, W1t, b41, c1,
        fused, 768, 0,
        nullptr, 0, 0,
        nullptr, 0, Nn, MT);

    // ---- GAT layer 1 (xl/xr in one launch) ----
    gemm16_dual_kernel<<<dim3(MT, 8), 256, 0, stream>>>(
        fused, 768, Wg0l, Wg0r, 256, g0_bl, g0_br, xlbuf, xrbuf, 512, Nn);
    gat_aggregate_kernel<<<dim3(Nn), 256, 0, stream>>>(
        xlbuf, xrbuf, g0_we, g0_att, g0_bias, offsets, src_sorted, ea_sorted,
        logit_buf, gbuf, 512, Nn);

    // ---- GAT layer 2 (output into fused cols 256..767) ----
    gemm16_dual_kernel<<<dim3(MT, 8), 256, 0, stream>>>(
        gbuf, 512, Wg1l, Wg1r, 512, g1_bl, g1_br, xlbuf, xrbuf, 512, Nn);
    gat_aggregate_kernel<<<dim3(Nn), 256, 0, stream>>>(
        xlbuf, xrbuf, g1_we, g1_att, g1_bias, offsets, src_sorted, ea_sorted,
        logit_buf, fused + 256, 768, Nn);

    // ---- fusion MLP ----
    gemm16_kernel<<<dim3(MT, 4), 256, 0, stream>>>(
        fused, 768, Wfc1, 768, fc1_b, nullptr, hfc1, 512, 1, Nn);
    fc2_kernel<<<dim3((Nn + 3) / 4), 256, 0, stream>>>(hfc1, fc2_w, fc2_b, out, Nn);
}

// Round 11
// 3130.435 us; speedup vs baseline: 1.3807x; 1.0742x over previous
//
#include <hip/hip_runtime.h>

#define DEV __device__ __forceinline__

typedef _Float16 f16;
typedef _Float16 f16x8 __attribute__((ext_vector_type(8)));
typedef _Float16 f16x2 __attribute__((ext_vector_type(2)));
typedef float f32x4 __attribute__((ext_vector_type(4)));

DEV float sigmoidf_(float x) { return 1.0f / (1.0f + __expf(-x)); }
DEV float tanhf2_(float x)   { return 1.0f - 2.0f / (__expf(2.0f * x) + 1.0f); }

// async global->LDS, 16B per lane. LDS dest = wave-uniform base + lane*16.
DEV void load_lds16(const void* g, void* l) {
    __builtin_amdgcn_global_load_lds(
        (const __attribute__((address_space(1))) char*)(const char*)g,
        (__attribute__((address_space(3))) char*)(unsigned int)(unsigned long long)(char*)l,
        16, 0, 0);
}

// LDS 16x32(f16) tile swizzle: chunk (row,ck) lives at physical slot
// ck ^ (row&3) ^ ((row>>2)&3). Loader permutes the GLOBAL chunk per lane;
// reader picks the matching physical slot (XOR involution).
DEV int swz(int row, int ck) { return ck ^ (row & 3) ^ ((row >> 2) & 3); }

// ---------------------------------------------------------------------------
// LSTM weight prep: Wt[1024][K] fp16, column-order chosen so that in the MFMA
// C-layout the 4 gates of a unit land in one lane's 4 j-fragments.
// dst row rd: T=rd>>7, p=rd&127, wh=(p>>6)&1, j=(p>>4)&3, c=p&15
//   unit u = T*32 + wh*16 + c ; gate g = j ; src row = g*256+u
// W0t: [1024,320] — cols 0..15 x, 16..271 h0, 272..319 zero (pad)
// ---------------------------------------------------------------------------
__global__ void prep_w0_kernel(const float* __restrict__ wih,
                               const float* __restrict__ whh,
                               f16* __restrict__ dst) {   // [1024,320]
    int idx = blockIdx.x * 256 + threadIdx.x;
    if (idx >= 1024 * 320) return;
    int rd = idx / 320, k = idx - rd * 320;
    int T = rd >> 7, p = rd & 127;
    int u = T * 32 + ((p >> 6) & 1) * 16 + (p & 15);
    int g = (p >> 4) & 3;
    int src = g * 256 + u;
    float v;
    if (k < 16)        v = wih[src * 16 + k];
    else if (k < 272)  v = whh[src * 256 + (k - 16)];
    else               v = 0.f;
    dst[idx] = (f16)v;
}

__global__ void prep_w1_kernel(const float* __restrict__ wih,
                               const float* __restrict__ whh,
                               f16* __restrict__ dst) {   // [1024,512]
    int idx = blockIdx.x * 256 + threadIdx.x;
    if (idx >= 1024 * 512) return;
    int rd = idx >> 9, k = idx & 511;
    int T = rd >> 7, p = rd & 127;
    int u = T * 32 + ((p >> 6) & 1) * 16 + (p & 15);
    int g = (p >> 4) & 3;
    int src = g * 256 + u;
    float v = (k < 256) ? wih[src * 256 + k] : whh[src * 256 + (k - 256)];
    dst[idx] = (f16)v;
}

__global__ void prep_bias4_kernel(const float* __restrict__ bi,
                                  const float* __restrict__ bh,
                                  float* __restrict__ dst) {  // [1024] = [u*4+g]
    int idx = blockIdx.x * 256 + threadIdx.x;
    if (idx >= 1024) return;
    int u = idx >> 2, g = idx & 3;
    dst[idx] = bi[g * 256 + u] + bh[g * 256 + u];
}

// generic [K,N] fp32 -> [N,K] fp16 transpose
__global__ void prep_wt_kernel(const float* __restrict__ src, f16* __restrict__ dst,
                               int K, int N) {
    int idx = blockIdx.x * 256 + threadIdx.x;
    if (idx >= K * N) return;
    int n = idx / K, k = idx - n * K;
    dst[idx] = (f16)src[(size_t)k * N + n];
}

// x_seq[:,0,:16] -> A0buf0 cols 0..15 (lda 320)
__global__ void prep_x0_kernel(const float* __restrict__ x_seq, f16* __restrict__ A0,
                               int Nn) {
    int idx = blockIdx.x * 256 + threadIdx.x;
    if (idx >= Nn * 16) return;
    int m = idx >> 4, f = idx & 15;
    A0[(size_t)m * 320 + f] = (f16)x_seq[(size_t)m * 960 + f];
}

// ---------------------------------------------------------------------------
// Shared MFMA helpers (32-col chunk of a 128x128 tile)
// ---------------------------------------------------------------------------
DEV void tile_load_chunk(const f16* __restrict__ A, int lda,
                         const f16* __restrict__ Bt, int K,
                         int m0, int n0, int k0,
                         f16* __restrict__ sA, f16* __restrict__ sB,
                         int w, int arow, int achk)
{
#pragma unroll
    for (int c = 0; c < 2; ++c) {
        int R = c * 64 + w * 16;
        load_lds16(A + (size_t)(m0 + R + arow) * lda + k0 + achk, sA + R * 32);
        load_lds16(Bt + (size_t)(n0 + R + arow) * K + k0 + achk, sB + R * 32);
    }
}

DEV void tile_compute_chunk(const f16* __restrict__ sA, const f16* __restrict__ sB,
                            f32x4 (&acc)[4][4], int wr, int wc, int frow, int fsl)
{
    f16x8 af[4], bf[4];
#pragma unroll
    for (int i = 0; i < 4; ++i)
        af[i] = *(const f16x8*)&sA[(wr + i * 16 + frow) * 32 + fsl];
#pragma unroll
    for (int j = 0; j < 4; ++j)
        bf[j] = *(const f16x8*)&sB[(wc + j * 16 + frow) * 32 + fsl];
#pragma unroll
    for (int i = 0; i < 4; ++i)
#pragma unroll
        for (int j = 0; j < 4; ++j)
            acc[i][j] = __builtin_amdgcn_mfma_f32_16x16x32_f16(af[i], bf[j], acc[i][j], 0, 0, 0);
}

// ---------------------------------------------------------------------------
// LSTM step core (f16 MFMA): gates = A @ Wt^T (+bias), cell update.
// Tile 128x128, 4 waves 2x2. Double-buffered 32-col chunks: loads for
// chunk k+1 issue right after the barrier, overlapping chunk k's MFMA.
// c-state prefetched before the K-loop. bx/by from XCD-swizzled id.
// ---------------------------------------------------------------------------
DEV void lstm_step_core(
    f16* __restrict__ sA, f16* __restrict__ sB,   // each [2*4096] f16
    int bx, int by,
    const f16* __restrict__ A, int lda, int K,
    const f16* __restrict__ Wt,
    const float* __restrict__ bias4,
    float* __restrict__ c_state,
    f16* __restrict__ hA, int ldhA, int offhA,
    f16* __restrict__ hB, int ldhB, int offhB,
    const float* __restrict__ xsrc, int tnext,
    int M)
{
    const int tid = threadIdx.x;
    const int w = tid >> 6, lane = tid & 63;
    const int m0 = bx * 128, n0 = by * 128;
    const int arow = lane >> 2;
    const int achk = swz(arow, lane & 3) * 8;
    const int frow = lane & 15, l4 = lane >> 4;
    const int fsl = swz(frow, l4) * 8;
    const int wr = (w >> 1) * 64, wc = (w & 1) * 64;

    // prefetch c-state (epilogue inputs) — K-loop covers the latency.
    const int u = by * 32 + (w & 1) * 16 + (lane & 15);
    const int rbase = m0 + wr + (lane >> 4) * 4;
    float cold[4][4];
#pragma unroll
    for (int i = 0; i < 4; ++i)
#pragma unroll
        for (int r = 0; r < 4; ++r)
            cold[i][r] = c_state[(size_t)(rbase + i * 16 + r) * 256 + u];

    f32x4 acc[4][4] = {};
    const int nch = K >> 5;

    tile_load_chunk(A, lda, Wt, K, m0, n0, 0, sA, sB, w, arow, achk);
    for (int kc = 0; kc < nch; ++kc) {
        __syncthreads();
        const int cur = (kc & 1) * 4096;
        if (kc + 1 < nch) {
            const int nxt = ((kc + 1) & 1) * 4096;
            tile_load_chunk(A, lda, Wt, K, m0, n0, (kc + 1) * 32,
                            sA + nxt, sB + nxt, w, arow, achk);
        }
        tile_compute_chunk(sA + cur, sB + cur, acc, wr, wc, frow, fsl);
    }

    // epilogue: lane owns unit u, acc[i][j][r] = gate j of row m
    const float4 bb = *(const float4*)&bias4[u * 4];
#pragma unroll
    for (int i = 0; i < 4; ++i) {
#pragma unroll
        for (int r = 0; r < 4; ++r) {
            int m = rbase + i * 16 + r;
            if (m < M) {
                float gi = sigmoidf_(acc[i][0][r] + bb.x);
                float gf = sigmoidf_(acc[i][1][r] + bb.y);
                float gg = tanhf2_(acc[i][2][r] + bb.z);
                float go = sigmoidf_(acc[i][3][r] + bb.w);
                float cn = gf * cold[i][r] + gi * gg;
                c_state[(size_t)m * 256 + u] = cn;
                f16 h = (f16)(go * tanhf2_(cn));
                hA[(size_t)m * ldhA + offhA + u] = h;
                if (hB) hB[(size_t)m * ldhB + offhB + u] = h;
            }
        }
    }
    // layer0 blocks (by==0) stage x_{t+1} into A0next cols 0..15
    if (xsrc && by == 0) {
        int row = tid >> 1, fb = (tid & 1) * 8;
        int m = m0 + row;
        if (m < M) {
            const float* xp = xsrc + (size_t)m * 960 + tnext * 16 + fb;
            f16* dp = hB + (size_t)m * ldhB + fb;
#pragma unroll
            for (int q = 0; q < 8; ++q) dp[q] = (f16)xp[q];
        }
    }
}

// solo (single-layer) LSTM step. Grid: mtPad8*8 linear, XCD-swizzled:
// l%8 = x%8 -> all 8 y-blocks of one x-tile land on one XCD (A/c L2 locality).
__global__ __launch_bounds__(256) void lstm_mfma_kernel(
    const f16* __restrict__ A, int lda, int K,
    const f16* __restrict__ Wt, const float* __restrict__ bias4,
    float* __restrict__ c_state,
    f16* __restrict__ hA, int ldhA, int offhA,
    f16* __restrict__ hB, int ldhB, int offhB,
    const float* __restrict__ xsrc, int tnext, int M, int mtiles)
{
    __shared__ __align__(16) f16 sA[2 * 4096];
    __shared__ __align__(16) f16 sB[2 * 4096];
    const int l = blockIdx.x;
    const int xcd = l & 7, q = l >> 3;
    const int y = q & 7, xhi = q >> 3;
    const int x = xhi * 8 + xcd;
    if (x >= mtiles) return;
    lstm_step_core(sA, sB, x, y, A, lda, K, Wt, bias4, c_state,
                   hA, ldhA, offhA, hB, ldhB, offhB, xsrc, tnext, M);
}

// merged: z=0 -> layer1(t), z=1 -> layer0(t+1). All 16 (y,z) blocks of one
// x-tile share an XCD.
__global__ __launch_bounds__(256) void lstm_dual_kernel(
    const f16* __restrict__ A1, const f16* __restrict__ W1t,
    const float* __restrict__ b41, float* __restrict__ c1,
    f16* __restrict__ h1A, int ldh1A, int offh1A,
    const f16* __restrict__ A0, const f16* __restrict__ W0t,
    const float* __restrict__ b40, float* __restrict__ c0,
    f16* __restrict__ h0A, int ldh0A, int offh0A,
    f16* __restrict__ h0B, int ldh0B, int offh0B,
    const float* __restrict__ xsrc, int tnext, int M, int mtiles)
{
    __shared__ __align__(16) f16 sA[2 * 4096];
    __shared__ __align__(16) f16 sB[2 * 4096];
    const int l = blockIdx.x;
    const int xcd = l & 7, q = l >> 3;
    const int yz = q & 15, xhi = q >> 4;
    const int x = xhi * 8 + xcd;
    if (x >= mtiles) return;
    const int y = yz & 7, z = yz >> 3;
    if (z == 0)
        lstm_step_core(sA, sB, x, y, A1, 512, 512, W1t, b41, c1,
                       h1A, ldh1A, offh1A, nullptr, 0, 0, nullptr, 0, M);
    else
        lstm_step_core(sA, sB, x, y, A0, 320, 320, W0t, b40, c0,
                       h0A, ldh0A, offh0A, h0B, ldh0B, offh0B, xsrc, tnext, M);
}

// ---------------------------------------------------------------------------
// Generic f16 MFMA GEMM (double-buffered): C = act(A @ Bt^T + bias)
// ---------------------------------------------------------------------------
__global__ __launch_bounds__(256) void gemm16_kernel(
    const f16* __restrict__ A, int lda,
    const f16* __restrict__ Bt, int K,
    const float* __restrict__ bias,
    f16* __restrict__ C16, float* __restrict__ C32, int ldc,
    int act, int M)
{
    __shared__ __align__(16) f16 sA[2 * 4096];
    __shared__ __align__(16) f16 sB[2 * 4096];
    const int tid = threadIdx.x;
    const int w = tid >> 6, lane = tid & 63;
    const int m0 = blockIdx.x * 128, n0 = blockIdx.y * 128;
    const int arow = lane >> 2;
    const int achk = swz(arow, lane & 3) * 8;
    const int frow = lane & 15, l4 = lane >> 4;
    const int fsl = swz(frow, l4) * 8;
    const int wr = (w >> 1) * 64, wcn = (w & 1) * 64;

    f32x4 acc[4][4] = {};
    const int nch = K >> 5;

    tile_load_chunk(A, lda, Bt, K, m0, n0, 0, sA, sB, w, arow, achk);
    for (int kc = 0; kc < nch; ++kc) {
        __syncthreads();
        const int cur = (kc & 1) * 4096;
        if (kc + 1 < nch) {
            const int nxt = ((kc + 1) & 1) * 4096;
            tile_load_chunk(A, lda, Bt, K, m0, n0, (kc + 1) * 32,
                            sA + nxt, sB + nxt, w, arow, achk);
        }
        tile_compute_chunk(sA + cur, sB + cur, acc, wr, wcn, frow, fsl);
    }

    const int rbase = m0 + wr + (lane >> 4) * 4;
#pragma unroll
    for (int i = 0; i < 4; ++i) {
#pragma unroll
        for (int r = 0; r < 4; ++r) {
            int m = rbase + i * 16 + r;
            if (m >= M) continue;
#pragma unroll
            for (int j = 0; j < 4; ++j) {
                int n = n0 + wcn + j * 16 + (lane & 15);
                float v = acc[i][j][r] + bias[n];
                if (act == 1) v = fmaxf(v, 0.f);
                if (C16) C16[(size_t)m * ldc + n] = (f16)v;
                else     C32[(size_t)m * ldc + n] = v;
            }
        }
    }
}

// dual-B variant: y<4 -> (Btl,biasl,Cl), y>=4 -> (Btr,biasr,Cr). fp16 out.
__global__ __launch_bounds__(256) void gemm16_dual_kernel(
    const f16* __restrict__ A, int lda,
    const f16* __restrict__ Btl, const f16* __restrict__ Btr, int K,
    const float* __restrict__ biasl, const float* __restrict__ biasr,
    f16* __restrict__ Cl, f16* __restrict__ Cr, int ldc, int M)
{
    __shared__ __align__(16) f16 sA[2 * 4096];
    __shared__ __align__(16) f16 sB[2 * 4096];
    const int side = blockIdx.y >> 2;
    const f16* Bt = side ? Btr : Btl;
    const float* bias = side ? biasr : biasl;
    f16* C16 = side ? Cr : Cl;
    const int tid = threadIdx.x;
    const int w = tid >> 6, lane = tid & 63;
    const int m0 = blockIdx.x * 128, n0 = (blockIdx.y & 3) * 128;
    const int arow = lane >> 2;
    const int achk = swz(arow, lane & 3) * 8;
    const int frow = lane & 15, l4 = lane >> 4;
    const int fsl = swz(frow, l4) * 8;
    const int wr = (w >> 1) * 64, wcn = (w & 1) * 64;

    f32x4 acc[4][4] = {};
    const int nch = K >> 5;

    tile_load_chunk(A, lda, Bt, K, m0, n0, 0, sA, sB, w, arow, achk);
    for (int kc = 0; kc < nch; ++kc) {
        __syncthreads();
        const int cur = (kc & 1) * 4096;
        if (kc + 1 < nch) {
            const int nxt = ((kc + 1) & 1) * 4096;
            tile_load_chunk(A, lda, Bt, K, m0, n0, (kc + 1) * 32,
                            sA + nxt, sB + nxt, w, arow, achk);
        }
        tile_compute_chunk(sA + cur, sB + cur, acc, wr, wcn, frow, fsl);
    }

    const int rbase = m0 + wr + (lane >> 4) * 4;
#pragma unroll
    for (int i = 0; i < 4; ++i) {
#pragma unroll
        for (int r = 0; r < 4; ++r) {
            int m = rbase + i * 16 + r;
            if (m >= M) continue;
#pragma unroll
            for (int j = 0; j < 4; ++j) {
                int n = n0 + wcn + j * 16 + (lane & 15);
                float v = acc[i][j][r] + bias[n];
                C16[(size_t)m * ldc + n] = (f16)v;
            }
        }
    }
}

// ---------------------------------------------------------------------------
// Edge preprocessing
// ---------------------------------------------------------------------------
__global__ void mean_sum_kernel(const float* __restrict__ a, int n, float* __restrict__ out) {
    __shared__ float s[256];
    float loc = 0.f;
    for (int i = blockIdx.x * 256 + threadIdx.x; i < n; i += gridDim.x * 256) loc += a[i];
    s[threadIdx.x] = loc;
    __syncthreads();
    for (int off = 128; off; off >>= 1) {
        if (threadIdx.x < off) s[threadIdx.x] += s[threadIdx.x + off];
        __syncthreads();
    }
    if (threadIdx.x == 0) atomicAdd(out, s[0]);
}

__global__ void hist_kernel(const int* __restrict__ ei, int Ne, int Nn,
                            int* __restrict__ counts) {
    int e = blockIdx.x * 256 + threadIdx.x;
    if (e >= Ne + Nn) return;
    int d = (e < Ne) ? ei[Ne + e] : (e - Ne);
    atomicAdd(&counts[d], 1);
}

__global__ void scan_kernel(const int* __restrict__ counts, int* __restrict__ offsets, int n) {
    __shared__ int s[256];
    int tid = threadIdx.x;
    int chunk = (n + 255) / 256;
    int b = tid * chunk;
    int loc = 0;
    for (int j = 0; j < chunk; ++j) { int i = b + j; if (i < n) loc += counts[i]; }
    s[tid] = loc;
    __syncthreads();
    for (int off = 1; off < 256; off <<= 1) {
        int v = (tid >= off) ? s[tid - off] : 0;
        __syncthreads();
        s[tid] += v;
        __syncthreads();
    }
    int run = (tid == 0) ? 0 : s[tid - 1];
    for (int j = 0; j < chunk; ++j) {
        int i = b + j;
        if (i < n) { offsets[i] = run; run += counts[i]; }
    }
    if (tid == 255) offsets[n] = run;
}

__global__ void scatter_kernel(const int* __restrict__ ei, const float* __restrict__ ea,
                               const float* __restrict__ sump, float inv_ne, int Ne, int Nn,
                               int* __restrict__ cursor, int* __restrict__ src_sorted,
                               float* __restrict__ ea_sorted) {
    int e = blockIdx.x * 256 + threadIdx.x;
    if (e >= Ne + Nn) return;
    int s, d; float a;
    if (e < Ne) { s = ei[e]; d = ei[Ne + e]; a = ea[e]; }
    else        { s = e - Ne; d = s; a = sump[0] * inv_ne; }
    int pos = atomicAdd(&cursor[d], 1);
    src_sorted[pos] = s;
    ea_sorted[pos] = a;
}

// ---------------------------------------------------------------------------
// GATv2 attention + aggregation (fp16 xl/xr), one block per dst node.
// ---------------------------------------------------------------------------
__global__ __launch_bounds__(256) void gat_aggregate_kernel(
    const f16* __restrict__ xl, const f16* __restrict__ xr,
    const float* __restrict__ we, const float* __restrict__ att,
    const float* __restrict__ bias,
    const int* __restrict__ offsets, const int* __restrict__ src_sorted,
    const float* __restrict__ ea_sorted,
    float* __restrict__ logit_buf, f16* __restrict__ out, int ldo, int N)
{
    __shared__ float s_xr[512], s_we[512], s_att[512];
    __shared__ float s_wmax[32], s_mx[8], s_den[8], s_rden[8];
    __shared__ float s_alpha[256];
    __shared__ int s_src[32];
    const int i = blockIdx.x;
    const int tid = threadIdx.x;
    s_xr[tid]       = (float)xr[(size_t)i * 512 + tid];
    s_xr[tid + 256] = (float)xr[(size_t)i * 512 + tid + 256];
    s_we[tid] = we[tid]; s_we[tid + 256] = we[tid + 256];
    s_att[tid] = att[tid]; s_att[tid + 256] = att[tid + 256];
    if (tid < 8) s_den[tid] = 0.f;
    __syncthreads();

    const int beg = offsets[i], end = offsets[i + 1];
    const int w = tid >> 6, lane = tid & 63;

    float wm[4] = {-1e30f, -1e30f, -1e30f, -1e30f};
    for (int e = beg + w; e < end; e += 4) {
        int s = src_sorted[e];
        float a = ea_sorted[e];
        float part[4];
#pragma unroll
        for (int cc = 0; cc < 4; ++cc) {
            int col = cc * 128 + lane * 2;
            f16x2 xv = *(const f16x2*)&xl[(size_t)s * 512 + col];
            float v0 = (float)xv.x + s_xr[col]     + a * s_we[col];
            float v1 = (float)xv.y + s_xr[col + 1] + a * s_we[col + 1];
            v0 = (v0 > 0.f) ? v0 : 0.2f * v0;
            v1 = (v1 > 0.f) ? v1 : 0.2f * v1;
            part[cc] = v0 * s_att[col] + v1 * s_att[col + 1];
        }
#pragma unroll
        for (int off = 16; off; off >>= 1)
#pragma unroll
            for (int cc = 0; cc < 4; ++cc) part[cc] += __shfl_xor(part[cc], off);
        if ((lane & 31) == 0) {
            int hb = lane >> 5;
#pragma unroll
            for (int cc = 0; cc < 4; ++cc) {
                logit_buf[(size_t)e * 8 + 2 * cc + hb] = part[cc];
                wm[cc] = fmaxf(wm[cc], part[cc]);
            }
        }
    }
    if ((lane & 31) == 0) {
        int hb = lane >> 5;
#pragma unroll
        for (int cc = 0; cc < 4; ++cc) s_wmax[w * 8 + 2 * cc + hb] = wm[cc];
    }
    __syncthreads();
    if (tid < 8) {
        float m = fmaxf(fmaxf(s_wmax[tid], s_wmax[8 + tid]),
                        fmaxf(s_wmax[16 + tid], s_wmax[24 + tid]));
        s_mx[tid] = m;
    }
    __syncthreads();

    for (int e = beg + tid; e < end; e += 256) {
#pragma unroll
        for (int h = 0; h < 8; ++h) {
            float ex = __expf(logit_buf[(size_t)e * 8 + h] - s_mx[h]);
            logit_buf[(size_t)e * 8 + h] = ex;
            atomicAdd(&s_den[h], ex);
        }
    }
    __syncthreads();
    if (tid < 8) s_rden[tid] = 1.f / s_den[tid];
    __syncthreads();

    float acc0 = 0.f, acc1 = 0.f;
    const int c2 = tid * 2, hh = tid >> 5;
    for (int chunk = beg; chunk < end; chunk += 32) {
        int cnt = min(32, end - chunk);
        if (tid < cnt) s_src[tid] = src_sorted[chunk + tid];
        int eo = tid >> 3, hq = tid & 7;
        if (eo < cnt) s_alpha[tid] = logit_buf[(size_t)(chunk + eo) * 8 + hq] * s_rden[hq];
        __syncthreads();
        for (int j = 0; j < cnt; ++j) {
            int s = s_src[j];
            f16x2 xv = *(const f16x2*)&xl[(size_t)s * 512 + c2];
            float al = s_alpha[j * 8 + hh];
            acc0 += al * (float)xv.x;
            acc1 += al * (float)xv.y;
        }
        __syncthreads();
    }
    float v0 = acc0 + bias[c2];
    float v1 = acc1 + bias[c2 + 1];
    v0 = (v0 > 0.f) ? v0 : __expf(v0) - 1.f;
    v1 = (v1 > 0.f) ? v1 : __expf(v1) - 1.f;
    f16x2 ov; ov.x = (f16)v0; ov.y = (f16)v1;
    *(f16x2*)&out[(size_t)i * ldo + c2] = ov;
}

// fc2: out[n] = H[n,:512] . w + b (fp32)
__global__ void fc2_kernel(const float* __restrict__ H, const float* __restrict__ w,
                           const float* __restrict__ b, float* __restrict__ out, int N) {
    int wv = threadIdx.x >> 6, lane = threadIdx.x & 63;
    int node = blockIdx.x * 4 + wv;
    if (node >= N) return;
    float s = 0.f;
#pragma unroll
    for (int j = 0; j < 8; ++j)
        s += H[(size_t)node * 512 + j * 64 + lane] * w[j * 64 + lane];
#pragma unroll
    for (int off = 32; off; off >>= 1) s += __shfl_xor(s, off, 64);
    if (lane == 0) out[node] = s + b[0];
}

// ---------------------------------------------------------------------------
extern "C" void kernel_launch(void* const* d_in, const int* in_sizes, int n_in,
                              void* d_out, int out_size, void* d_ws, size_t ws_size,
                              hipStream_t stream) {
    const float* x_seq     = (const float*)d_in[0];
    const int*   edge_index= (const int*)d_in[1];
    const float* edge_attr = (const float*)d_in[2];
    const float* w_ih0 = (const float*)d_in[3];
    const float* w_hh0 = (const float*)d_in[4];
    const float* b_ih0 = (const float*)d_in[5];
    const float* b_hh0 = (const float*)d_in[6];
    const float* w_ih1 = (const float*)d_in[7];
    const float* w_hh1 = (const float*)d_in[8];
    const float* b_ih1 = (const float*)d_in[9];
    const float* b_hh1 = (const float*)d_in[10];
    const float* g0_wl = (const float*)d_in[11];
    const float* g0_bl = (const float*)d_in[12];
    const float* g0_wr = (const float*)d_in[13];
    const float* g0_br = (const float*)d_in[14];
    const float* g0_we = (const float*)d_in[15];
    const float* g0_att= (const float*)d_in[16];
    const float* g0_bias=(const float*)d_in[17];
    const float* g1_wl = (const float*)d_in[18];
    const float* g1_bl = (const float*)d_in[19];
    const float* g1_wr = (const float*)d_in[20];
    const float* g1_br = (const float*)d_in[21];
    const float* g1_we = (const float*)d_in[22];
    const float* g1_att= (const float*)d_in[23];
    const float* g1_bias=(const float*)d_in[24];
    const float* fc1_w = (const float*)d_in[25];
    const float* fc1_b = (const float*)d_in[26];
    const float* fc2_w = (const float*)d_in[27];
    const float* fc2_b = (const float*)d_in[28];
    float* out = (float*)d_out;

    const int Nn = in_sizes[0] / (60 * 16);   // 10000
    const int Ne = in_sizes[1] / 2;           // 320000
    const int Etot = Ne + Nn;
    const int MT = (Nn + 127) / 128;          // 79
    const int Mpad = MT * 128;                // 10112
    const int MTpad8 = ((MT + 7) / 8) * 8;    // 80 (x padded for swizzle)

    size_t off = 0;
    auto alloc = [&](size_t bytes) -> void* {
        void* r = (char*)d_ws + off;
        off += (bytes + 255) & ~(size_t)255;
        return r;
    };
    f16* W0t   = (f16*)alloc((size_t)1024 * 320 * 2);
    f16* W1t   = (f16*)alloc((size_t)1024 * 512 * 2);
    float* b40 = (float*)alloc(1024 * 4);
    float* b41 = (float*)alloc(1024 * 4);
    f16* Wg0l  = (f16*)alloc((size_t)512 * 256 * 2);
    f16* Wg0r  = (f16*)alloc((size_t)512 * 256 * 2);
    f16* Wg1l  = (f16*)alloc((size_t)512 * 512 * 2);
    f16* Wg1r  = (f16*)alloc((size_t)512 * 512 * 2);
    f16* Wfc1  = (f16*)alloc((size_t)512 * 768 * 2);
    f16* A0b[2]; A0b[0] = (f16*)alloc((size_t)Mpad * 320 * 2);
                 A0b[1] = (f16*)alloc((size_t)Mpad * 320 * 2);
    f16* A1b[2]; A1b[0] = (f16*)alloc((size_t)Mpad * 512 * 2);
                 A1b[1] = (f16*)alloc((size_t)Mpad * 512 * 2);
    float* c0  = (float*)alloc((size_t)Mpad * 256 * 4);
    float* c1  = (float*)alloc((size_t)Mpad * 256 * 4);
    f16* fused = (f16*)alloc((size_t)Mpad * 768 * 2);
    f16* xlbuf = (f16*)alloc((size_t)Mpad * 512 * 2);
    f16* xrbuf = (f16*)alloc((size_t)Mpad * 512 * 2);
    f16* gbuf  = (f16*)alloc((size_t)Mpad * 512 * 2);
    float* hfc1= (float*)alloc((size_t)Mpad * 512 * 4);
    float* logit_buf = (float*)alloc((size_t)Etot * 8 * 4);
    int* counts  = (int*)alloc((size_t)Nn * 4);
    int* offsets = (int*)alloc((size_t)(Nn + 1) * 4);
    int* cursor  = (int*)alloc((size_t)Nn * 4);
    int* src_sorted = (int*)alloc((size_t)Etot * 4);
    float* ea_sorted = (float*)alloc((size_t)Etot * 4);
    float* meanp = (float*)alloc(256);

    // ---- weight / state prep ----
    prep_w0_kernel<<<dim3((1024 * 320 + 255) / 256), 256, 0, stream>>>(w_ih0, w_hh0, W0t);
    prep_w1_kernel<<<dim3((1024 * 512 + 255) / 256), 256, 0, stream>>>(w_ih1, w_hh1, W1t);
    prep_bias4_kernel<<<dim3(4), 256, 0, stream>>>(b_ih0, b_hh0, b40);
    prep_bias4_kernel<<<dim3(4), 256, 0, stream>>>(b_ih1, b_hh1, b41);
    prep_wt_kernel<<<dim3((256 * 512 + 255) / 256), 256, 0, stream>>>(g0_wl, Wg0l, 256, 512);
    prep_wt_kernel<<<dim3((256 * 512 + 255) / 256), 256, 0, stream>>>(g0_wr, Wg0r, 256, 512);
    prep_wt_kernel<<<dim3((512 * 512 + 255) / 256), 256, 0, stream>>>(g1_wl, Wg1l, 512, 512);
    prep_wt_kernel<<<dim3((512 * 512 + 255) / 256), 256, 0, stream>>>(g1_wr, Wg1r, 512, 512);
    prep_wt_kernel<<<dim3((768 * 512 + 255) / 256), 256, 0, stream>>>(fc1_w, Wfc1, 768, 512);
    hipMemsetAsync(A0b[0], 0, (size_t)Mpad * 320 * 2, stream);
    hipMemsetAsync(A0b[1], 0, (size_t)Mpad * 320 * 2, stream);
    hipMemsetAsync(A1b[0], 0, (size_t)Mpad * 512 * 2, stream);
    hipMemsetAsync(c0, 0, (size_t)Mpad * 256 * 4, stream);
    hipMemsetAsync(c1, 0, (size_t)Mpad * 256 * 4, stream);
    prep_x0_kernel<<<dim3((Nn * 16 + 255) / 256), 256, 0, stream>>>(x_seq, A0b[0], Nn);

    // ---- edge prep (CSR by dst) ----
    hipMemsetAsync(meanp, 0, 4, stream);
    hipMemsetAsync(counts, 0, (size_t)Nn * 4, stream);
    mean_sum_kernel<<<dim3(256), 256, 0, stream>>>(edge_attr, Ne, meanp);
    hist_kernel<<<dim3((Etot + 255) / 256), 256, 0, stream>>>(edge_index, Ne, Nn, counts);
    scan_kernel<<<dim3(1), 256, 0, stream>>>(counts, offsets, Nn);
    hipMemcpyAsync(cursor, offsets, (size_t)Nn * 4, hipMemcpyDeviceToDevice, stream);
    scatter_kernel<<<dim3((Etot + 255) / 256), 256, 0, stream>>>(
        edge_index, edge_attr, meanp, 1.0f / (float)Ne, Ne, Nn, cursor, src_sorted, ea_sorted);

    // ---- 2-layer LSTM, 60 steps; L1(t) and L0(t+1) co-scheduled, XCD-swizzled ----
    const int solo_grid = MTpad8 * 8;    // 640
    const int dual_grid = MTpad8 * 16;   // 1280
    // L0(0)
    lstm_mfma_kernel<<<dim3(solo_grid), 256, 0, stream>>>(
        A0b[0], 320, 320, W0t, b40, c0,
        A1b[0], 512, 0,
        A0b[1], 320, 16,
        x_seq, 1, Nn, MT);
    // merged L1(k) + L0(k+1), k = 0..58
    for (int k = 0; k < 59; ++k) {
        lstm_dual_kernel<<<dim3(dual_grid), 256, 0, stream>>>(
            A1b[k & 1], W1t, b41, c1,
            A1b[(k + 1) & 1], 512, 256,
            A0b[(k + 1) & 1], W0t, b40, c0,
            A1b[(k + 1) & 1], 512, 0,
            A0b[k & 1], 320, 16,
            (k + 1 < 59) ? x_seq : nullptr, k + 2, Nn, MT);
    }
    // L1(59): write h1_59 (node) directly into fused cols 0..255
    lstm_mfma_kernel<<<dim3(solo_grid), 256, 0, stream>>>(
        A1b[1], 512, 512, W1t, b41, c1,
        fused, 768, 0,
        nullptr, 0, 0,
        nullptr, 0, Nn, MT);

    // ---- GAT layer 1 (xl/xr in one launch) ----
    gemm16_dual_kernel<<<dim3(MT, 8), 256, 0, stream>>>(
        fused, 768, Wg0l, Wg0r, 256, g0_bl, g0_br, xlbuf, xrbuf, 512, Nn);
    gat_aggregate_kernel<<<dim3(Nn), 256, 0, stream>>>(
        xlbuf, xrbuf, g0_we, g0_att, g0_bias, offsets, src_sorted, ea_sorted,
        logit_buf, gbuf, 512, Nn);

    // ---- GAT layer 2 (output into fused cols 256..767) ----
    gemm16_dual_kernel<<<dim3(MT, 8), 256, 0, stream>>>(
        gbuf, 512, Wg1l, Wg1r, 512, g1_bl, g1_br, xlbuf, xrbuf, 512, Nn);
    gat_aggregate_kernel<<<dim3(Nn), 256, 0, stream>>>(
        xlbuf, xrbuf, g1_we, g1_att, g1_bias, offsets, src_sorted, ea_sorted,
        logit_buf, fused + 256, 768, Nn);

    // ---- fusion MLP ----
    gemm16_kernel<<<dim3(MT, 4), 256, 0, stream>>>(
        fused, 768, Wfc1, 768, fc1_b, nullptr, hfc1, 512, 1, Nn);
    fc2_kernel<<<dim3((Nn + 3) / 4), 256, 0, stream>>>(hfc1, fc2_w, fc2_b, out, Nn);
}